// Round 4
// baseline (631.244 us; speedup 1.0000x reference)
//
#include <hip/hip_runtime.h>
#include <stdint.h>

#define NUM_HEADS 12
#define HEAD_DIM  64
#define HWDIM     56
#define PHDIM     28
#define NTOK      785     // 28*28+1
#define NIN       3137    // 56*56+1
#define BATCH     16
#define DMODEL    768
#define BHCNT     192     // BATCH*NUM_HEADS

typedef __attribute__((ext_vector_type(8))) short bf16x8;
typedef __attribute__((ext_vector_type(4))) short s16x4;
typedef __attribute__((ext_vector_type(4))) float f32x4;
typedef __attribute__((ext_vector_type(2))) unsigned int u32x2;

static __device__ __forceinline__ float bf2f(short s) {
  unsigned u = ((unsigned)(unsigned short)s) << 16;
  float f; __builtin_memcpy(&f, &u, 4); return f;
}
static __device__ __forceinline__ short f2bf(float f) {
  unsigned u; __builtin_memcpy(&u, &f, 4);
  unsigned r = u + 0x7FFFu + ((u >> 16) & 1u);
  return (short)(r >> 16);
}

#if defined(__has_builtin)
#if __has_builtin(__builtin_amdgcn_global_load_lds)
#define HAVE_GLLDS 1
#endif
#endif

static __device__ __forceinline__ void gl_lds16(const short* g, short* l) {
#ifdef HAVE_GLLDS
  __builtin_amdgcn_global_load_lds(
      (const __attribute__((address_space(1))) void*)g,
      (__attribute__((address_space(3))) void*)l, 16, 0, 0);
#else
  int lane = threadIdx.x & 63;
  *(bf16x8*)(l + lane * 8) = *(const bf16x8*)g;
#endif
}

// ---------------------------------------------------------------- pool + LN
__global__ __launch_bounds__(192) void pool_ln_kernel(
    const float* __restrict__ x,
    const float* __restrict__ wq9, const float* __restrict__ wk9, const float* __restrict__ wv9,
    const float* __restrict__ gq, const float* __restrict__ bq,
    const float* __restrict__ gk, const float* __restrict__ bk,
    const float* __restrict__ gv, const float* __restrict__ bv,
    short* __restrict__ Pq, short* __restrict__ Pk, short* __restrict__ Pv)
{
  __shared__ __align__(16) float wt_s[3][9][64];   // [conv][tap][c]
  int tid = threadIdx.x;
  int blk = blockIdx.x;
  int b = blk / 197;
  int n0 = (blk - b * 197) * 4;

  for (int idx = tid; idx < 3 * 576; idx += 192) {
    int conv = idx / 576, rem = idx - conv * 576;
    int c = rem / 9, tap = rem - c * 9;
    const float* wsrc = (conv == 0) ? wq9 : (conv == 1) ? wk9 : wv9;
    wt_s[conv][tap][c] = wsrc[c * 9 + tap];
  }
  __syncthreads();

  int ch0 = tid * 4;
  int c4 = ch0 & 63;
  f32x4 g_q = *(const f32x4*)&gq[c4], b_q = *(const f32x4*)&bq[c4];
  f32x4 g_k = *(const f32x4*)&gk[c4], b_k = *(const f32x4*)&bk[c4];
  f32x4 g_v = *(const f32x4*)&gv[c4], b_v = *(const f32x4*)&bv[c4];

  for (int tt = 0; tt < 4; ++tt) {
    int n = n0 + tt;
    if (n >= NTOK) break;
    f32x4 aq = (f32x4){0.f, 0.f, 0.f, 0.f}, ak = aq, av = aq;
    if (n == 0) {
      f32x4 x4 = *(const f32x4*)&x[((size_t)b * NIN) * DMODEL + ch0];
      aq = ak = av = x4;
    } else {
      int s = n - 1;
      int i = s / PHDIM, j = s - i * PHDIM;
#pragma unroll
      for (int di = 0; di < 3; ++di) {
        int ii = 2 * i - 1 + di;
        if (ii < 0 || ii >= HWDIM) continue;
#pragma unroll
        for (int dj = 0; dj < 3; ++dj) {
          int jj = 2 * j - 1 + dj;
          if (jj < 0 || jj >= HWDIM) continue;
          f32x4 x4 = *(const f32x4*)&x[((size_t)b * NIN + 1 + ii * HWDIM + jj) * DMODEL + ch0];
          int tap = di * 3 + dj;
          f32x4 w0 = *(const f32x4*)&wt_s[0][tap][c4];
          f32x4 w1 = *(const f32x4*)&wt_s[1][tap][c4];
          f32x4 w2 = *(const f32x4*)&wt_s[2][tap][c4];
          aq += w0 * x4; ak += w1 * x4; av += w2 * x4;
        }
      }
    }
    size_t obase = ((size_t)b * NTOK + n) * DMODEL + ch0;
    {
      float sm = aq[0] + aq[1] + aq[2] + aq[3];
#pragma unroll
      for (int m = 1; m < 16; m <<= 1) sm += __shfl_xor(sm, m);
      float mn = sm * (1.f / 64.f);
      f32x4 d = aq - mn;
      float vs = d[0]*d[0] + d[1]*d[1] + d[2]*d[2] + d[3]*d[3];
#pragma unroll
      for (int m = 1; m < 16; m <<= 1) vs += __shfl_xor(vs, m);
      float rs = rsqrtf(vs * (1.f / 64.f) + 1e-5f);
      s16x4 o;
#pragma unroll
      for (int e = 0; e < 4; ++e) o[e] = f2bf(d[e] * rs * g_q[e] + b_q[e]);
      *(s16x4*)&Pq[obase] = o;
    }
    {
      float sm = ak[0] + ak[1] + ak[2] + ak[3];
#pragma unroll
      for (int m = 1; m < 16; m <<= 1) sm += __shfl_xor(sm, m);
      float mn = sm * (1.f / 64.f);
      f32x4 d = ak - mn;
      float vs = d[0]*d[0] + d[1]*d[1] + d[2]*d[2] + d[3]*d[3];
#pragma unroll
      for (int m = 1; m < 16; m <<= 1) vs += __shfl_xor(vs, m);
      float rs = rsqrtf(vs * (1.f / 64.f) + 1e-5f);
      s16x4 o;
#pragma unroll
      for (int e = 0; e < 4; ++e) o[e] = f2bf(d[e] * rs * g_k[e] + b_k[e]);
      *(s16x4*)&Pk[obase] = o;
    }
    {
      float sm = av[0] + av[1] + av[2] + av[3];
#pragma unroll
      for (int m = 1; m < 16; m <<= 1) sm += __shfl_xor(sm, m);
      float mn = sm * (1.f / 64.f);
      f32x4 d = av - mn;
      float vs = d[0]*d[0] + d[1]*d[1] + d[2]*d[2] + d[3]*d[3];
#pragma unroll
      for (int m = 1; m < 16; m <<= 1) vs += __shfl_xor(vs, m);
      float rs = rsqrtf(vs * (1.f / 64.f) + 1e-5f);
      s16x4 o;
#pragma unroll
      for (int e = 0; e < 4; ++e) o[e] = f2bf(d[e] * rs * g_v[e] + b_v[e]);
      *(s16x4*)&Pv[obase] = o;
    }
  }
}

// ------------------------------------------------- weight transpose fp32->bf16
__global__ __launch_bounds__(256) void trans_kernel(
    const float* __restrict__ s0, const float* __restrict__ s1,
    const float* __restrict__ s2, const float* __restrict__ s3,
    short* __restrict__ d0, short* __restrict__ d1,
    short* __restrict__ d2, short* __restrict__ d3)
{
  __shared__ float tile[32][33];
  int z = blockIdx.z;
  const float* s = (z == 0) ? s0 : (z == 1) ? s1 : (z == 2) ? s2 : s3;
  short* d = (z == 0) ? d0 : (z == 1) ? d1 : (z == 2) ? d2 : d3;
  int k0 = blockIdx.x * 32, n0 = blockIdx.y * 32;
  int tx = threadIdx.x, ty = threadIdx.y;   // 32 x 8
#pragma unroll
  for (int jj = 0; jj < 4; ++jj)
    tile[ty + jj * 8][tx] = s[(size_t)(k0 + ty + jj * 8) * DMODEL + n0 + tx];
  __syncthreads();
#pragma unroll
  for (int jj = 0; jj < 4; ++jj)
    d[(size_t)(n0 + ty + jj * 8) * DMODEL + k0 + tx] = f2bf(tile[tx][ty + jj * 8]);
}

// ------------------------------------------------------------- bf16 MFMA GEMM
// C[M,N] = A[M,K=768] @ Bt[N,768]^T + bias
// mode0: fp32 row-major out, bias[col]
// mode1: bf16 out in (B,12,785,64) layout, bias[col]
// mode2: bf16 out transposed (B*768 rows, 785 cols): out[(b*768+row)*785+n], bias[row]
__global__ __launch_bounds__(256) void gemm2_kernel(
    const short* __restrict__ A, const short* __restrict__ Bt,
    const float* __restrict__ bias, void* __restrict__ outp,
    int M, int Nn, int mode)
{
  const int K = DMODEL;
  __shared__ short As[128 * 32];
  __shared__ short Bs[128 * 32];
  int tid = threadIdx.x;
  int wid = tid >> 6, lane = tid & 63;
  int lg = lane >> 4, lq = lane & 15;
  int wm = wid >> 1, wn = wid & 1;
  int rowbase = blockIdx.x * 128;
  int colbase = blockIdx.y * 128;

  f32x4 acc[4][4];
#pragma unroll
  for (int i = 0; i < 4; ++i)
#pragma unroll
    for (int j = 0; j < 4; ++j) acc[i][j] = (f32x4){0.f, 0.f, 0.f, 0.f};

  int srow = tid >> 2;
  int scol = (tid & 3) * 8;
  int ar0 = min(rowbase + srow, M - 1);
  int ar1 = min(rowbase + 64 + srow, M - 1);
  int br0 = min(colbase + srow, Nn - 1);
  int br1 = min(colbase + 64 + srow, Nn - 1);
  const short* Ag0 = A + (size_t)ar0 * K + scol;
  const short* Ag1 = A + (size_t)ar1 * K + scol;
  const short* Bg0 = Bt + (size_t)br0 * K + scol;
  const short* Bg1 = Bt + (size_t)br1 * K + scol;
  short* AsW0 = As + wid * 512;
  short* AsW1 = As + 2048 + wid * 512;
  short* BsW0 = Bs + wid * 512;
  short* BsW1 = Bs + 2048 + wid * 512;

  for (int kt = 0; kt < K; kt += 32) {
    __syncthreads();
    gl_lds16(Ag0 + kt, AsW0);
    gl_lds16(Ag1 + kt, AsW1);
    gl_lds16(Bg0 + kt, BsW0);
    gl_lds16(Bg1 + kt, BsW1);
    __syncthreads();
    bf16x8 aFrag[4], bFrag[4];
#pragma unroll
    for (int mi = 0; mi < 4; ++mi)
      aFrag[mi] = *(const bf16x8*)&As[(wm * 64 + mi * 16 + lq) * 32 + lg * 8];
#pragma unroll
    for (int ni = 0; ni < 4; ++ni)
      bFrag[ni] = *(const bf16x8*)&Bs[(wn * 64 + ni * 16 + lq) * 32 + lg * 8];
#pragma unroll
    for (int mi = 0; mi < 4; ++mi)
#pragma unroll
      for (int ni = 0; ni < 4; ++ni)
        acc[mi][ni] = __builtin_amdgcn_mfma_f32_16x16x32_bf16(aFrag[mi], bFrag[ni], acc[mi][ni], 0, 0, 0);
  }

#pragma unroll
  for (int mi = 0; mi < 4; ++mi) {
    int rowq = rowbase + wm * 64 + mi * 16 + lg * 4;
#pragma unroll
    for (int r = 0; r < 4; ++r) {
      int row = rowq + r;
      if (row < M) {
        if (mode == 2) {
          float bb = bias[row];
#pragma unroll
          for (int ni = 0; ni < 4; ++ni) {
            int col = colbase + wn * 64 + ni * 16 + lq;
            if (col < Nn) {
              int b = col / NTOK, n = col - b * NTOK;
              float v = acc[mi][ni][r] + bb;
              ((short*)outp)[((size_t)b * DMODEL + row) * NTOK + n] = f2bf(v);
            }
          }
        } else {
          int bb = row / NTOK;
          int nn = row - bb * NTOK;
#pragma unroll
          for (int ni = 0; ni < 4; ++ni) {
            int col = colbase + wn * 64 + ni * 16 + lq;
            float v = acc[mi][ni][r] + bias[col];
            if (mode == 0) {
              ((float*)outp)[(size_t)row * DMODEL + col] = v;
            } else {
              ((short*)outp)[(((size_t)(bb * NUM_HEADS + (col >> 6)) * NTOK + nn) << 6) + (col & 63)] = f2bf(v);
            }
          }
        }
      }
    }
  }
}

// -------------------------------------------------------- rel-pos bias tables
// transposed output: RelHt[bh][kk][qrow] (28 x 784 per bh)
__global__ __launch_bounds__(256) void relbias_kernel(
    const short* __restrict__ qh, const float* __restrict__ rph,
    const float* __restrict__ rpw, float* __restrict__ RelHt, float* __restrict__ RelWt)
{
  int line = blockIdx.x;   // i (mode0) or j (mode1)
  int bh = blockIdx.y;
  int mode = blockIdx.z;
  __shared__ __align__(16) float qt_s[28 * 68];
  __shared__ __align__(16) float rt_s[28 * 68];
  int tid = threadIdx.x;
  const float* rp = (mode == 0) ? rph : rpw;
  for (int idx = tid; idx < 28 * 64; idx += 256) {
    int rr = idx >> 6, c = idx & 63;
    int qi = (mode == 0) ? (1 + line * PHDIM + rr) : (1 + rr * PHDIM + line);
    qt_s[rr * 68 + c] = bf2f(qh[((size_t)bh * NTOK + qi) * HEAD_DIM + c]);
    rt_s[rr * 68 + c] = rp[(line - rr + 27) * HEAD_DIM + c];
  }
  __syncthreads();
  float* dst = (mode == 0) ? RelHt : RelWt;
  for (int o = tid; o < 784; o += 256) {
    int kk = o / PHDIM, rr = o - kk * PHDIM;
    const f32x4* qa = (const f32x4*)&qt_s[rr * 68];
    const f32x4* ra = (const f32x4*)&rt_s[kk * 68];
    f32x4 a4 = (f32x4){0.f, 0.f, 0.f, 0.f};
#pragma unroll
    for (int i = 0; i < 16; ++i) a4 += qa[i] * ra[i];
    float s = a4[0] + a4[1] + a4[2] + a4[3];
    int qrow = (mode == 0) ? (line * PHDIM + rr) : (rr * PHDIM + line);
    dst[((size_t)bh * PHDIM + kk) * 784 + qrow] = s;
  }
}

// ------------------------------------------------------------ flash attention
// swapped QK^T; V^T from global (precomputed); no per-step barriers.
__global__ __launch_bounds__(256) void flash3_kernel(
    const short* __restrict__ qh, const short* __restrict__ kh, const short* __restrict__ vtg,
    const float* __restrict__ RelHt, const float* __restrict__ RelWt,
    short* __restrict__ Afin)
{
  int id = blockIdx.x;
  int slot = id >> 3;
  int bh = (id & 7) * 24 + slot / 13;   // all 13 q-tiles of a bh on one XCD
  int qt = slot - (slot / 13) * 13;
  int qbase = qt * 64;
  int tid = threadIdx.x, wid = tid >> 6, lane = tid & 63;
  int lg = lane >> 4, lq = lane & 15;

  __shared__ __align__(16) float relh_t[28][64];
  __shared__ __align__(16) float relw_t[28][64];
  __shared__ __align__(16) short pbuf[4][16 * 64];
  __shared__ __align__(16) float axl[4][16];

  // stage rel tables transposed: col = q_local
  for (int idx = tid; idx < 28 * 64; idx += 256) {
    int kk = idx >> 6, ql = idx & 63;
    int qi = qbase + ql;
    float rh = 0.f, rw = 0.f;
    if (qi >= 1 && qi < NTOK) {
      rh = RelHt[((size_t)bh * PHDIM + kk) * 784 + qi - 1];
      rw = RelWt[((size_t)bh * PHDIM + kk) * 784 + qi - 1];
    }
    relh_t[kk][ql] = rh; relw_t[kk][ql] = rw;
  }
  __syncthreads();

  int qi0 = qbase + wid * 16 + lq;
  int qiq = min(qi0, NTOK - 1);
  const short* qrow = qh + ((size_t)bh * NTOK + qiq) * HEAD_DIM;
  bf16x8 bq0 = *(const bf16x8*)(qrow + lg * 8);
  bf16x8 bq1 = *(const bf16x8*)(qrow + 32 + lg * 8);

  float m_l = -3e30f, l_l = 0.f;
  f32x4 acc[4];
#pragma unroll
  for (int ch = 0; ch < 4; ++ch) acc[ch] = (f32x4){0.f, 0.f, 0.f, 0.f};

  const float scale = 0.125f;
  int q_local = wid * 16 + lq;
  const short* vbase = vtg + (size_t)bh * 64 * NTOK;

  for (int step = 0; step < 13; ++step) {
    int kvb = step * 64;

    float p[16];
#pragma unroll
    for (int kt = 0; kt < 4; ++kt) {
      int krow_i = min(kvb + kt * 16 + lq, NTOK - 1);
      const short* krow = kh + ((size_t)bh * NTOK + krow_i) * HEAD_DIM;
      bf16x8 aK0 = *(const bf16x8*)(krow + lg * 8);
      bf16x8 aK1 = *(const bf16x8*)(krow + 32 + lg * 8);
      f32x4 s = (f32x4){0.f, 0.f, 0.f, 0.f};
      s = __builtin_amdgcn_mfma_f32_16x16x32_bf16(aK0, bq0, s, 0, 0, 0);
      s = __builtin_amdgcn_mfma_f32_16x16x32_bf16(aK1, bq1, s, 0, 0, 0);
#pragma unroll
      for (int r = 0; r < 4; ++r) {
        int key = kvb + kt * 16 + lg * 4 + r;
        float v = s[r] * scale;
        if (key >= 1 && key < NTOK) {
          int km1 = key - 1;
          int ki = km1 / PHDIM, kj = km1 - ki * PHDIM;
          v += relh_t[ki][q_local] + relw_t[kj][q_local];
        }
        if (key >= NTOK) v = -3e30f;
        p[kt * 4 + r] = v;
      }
    }

    // softmax (q-row local to lane-column lq; cross lg via 2 shfls)
    float pm = p[0];
#pragma unroll
    for (int i = 1; i < 16; ++i) pm = fmaxf(pm, p[i]);
    pm = fmaxf(pm, __shfl_xor(pm, 16));
    pm = fmaxf(pm, __shfl_xor(pm, 32));
    if (!__all(pm - m_l <= 8.f)) {   // defer-rescale (T13)
      float mnew = fmaxf(m_l, pm);
      float alpha = __expf(m_l - mnew);
      m_l = mnew;
      l_l *= alpha;
      if (lg == 0) axl[wid][lq] = alpha;
      f32x4 av = *(const f32x4*)&axl[wid][lg * 4];
#pragma unroll
      for (int ch = 0; ch < 4; ++ch)
#pragma unroll
        for (int r = 0; r < 4; ++r) acc[ch][r] *= av[r];
    }
    float ps = 0.f;
#pragma unroll
    for (int i = 0; i < 16; ++i) { p[i] = __expf(p[i] - m_l); ps += p[i]; }
    ps += __shfl_xor(ps, 16);
    ps += __shfl_xor(ps, 32);
    l_l += ps;

    // pack P -> per-wave LDS (b64 writes, XOR-swizzled 16B blocks)
    short* pw = (short*)pbuf[wid];
#pragma unroll
    for (int kt = 0; kt < 4; ++kt) {
      unsigned lo = ((unsigned)(unsigned short)f2bf(p[kt * 4 + 0])) |
                    ((unsigned)(unsigned short)f2bf(p[kt * 4 + 1]) << 16);
      unsigned hi = ((unsigned)(unsigned short)f2bf(p[kt * 4 + 2])) |
                    ((unsigned)(unsigned short)f2bf(p[kt * 4 + 3]) << 16);
      int byte = (lq * 128 + (kt * 16 + lg * 4) * 2) ^ ((lq & 7) << 4);
      u32x2 pk; pk[0] = lo; pk[1] = hi;
      *(u32x2*)((char*)pw + byte) = pk;
    }
    // PV: pa from LDS, V^T fragments straight from global (L2-resident)
#pragma unroll
    for (int kc = 0; kc < 2; ++kc) {
      int pbyte = (lq * 128 + kc * 64 + lg * 16) ^ ((lq & 7) << 4);
      bf16x8 pa = *(const bf16x8*)((char*)pw + pbyte);
#pragma unroll
      for (int ch = 0; ch < 4; ++ch) {
        int d = ch * 16 + lq;
        bf16x8 bv = *(const bf16x8*)(vbase + (size_t)d * NTOK + kvb + kc * 32 + lg * 8);
        acc[ch] = __builtin_amdgcn_mfma_f32_16x16x32_bf16(pa, bv, acc[ch], 0, 0, 0);
      }
    }
  }

  if (lg == 0) axl[wid][lq] = l_l;
  f32x4 lv = *(const f32x4*)&axl[wid][lg * 4];
  int b = bh / NUM_HEADS, h = bh - b * NUM_HEADS;
#pragma unroll
  for (int r = 0; r < 4; ++r) {
    int qi = qbase + wid * 16 + lg * 4 + r;
    if (qi < NTOK) {
      float inv = 1.f / lv[r];
#pragma unroll
      for (int ch = 0; ch < 4; ++ch) {
        int d = ch * 16 + lq;
        float o = acc[ch][r] * inv + bf2f(qh[((size_t)bh * NTOK + qi) * HEAD_DIM + d]);
        Afin[((size_t)b * NTOK + qi) * DMODEL + h * HEAD_DIM + d] = f2bf(o);
      }
    }
  }
}

// ------------------------------------------------------------------- launcher
extern "C" void kernel_launch(void* const* d_in, const int* in_sizes, int n_in,
                              void* d_out, int out_size, void* d_ws, size_t ws_size,
                              hipStream_t stream)
{
  (void)in_sizes; (void)n_in; (void)out_size; (void)ws_size;
  const float* x   = (const float*)d_in[0];
  const float* pqw = (const float*)d_in[1];
  const float* pkw = (const float*)d_in[2];
  const float* pvw = (const float*)d_in[3];
  const float* gq  = (const float*)d_in[4];
  const float* bq_ = (const float*)d_in[5];
  const float* gk  = (const float*)d_in[6];
  const float* bk_ = (const float*)d_in[7];
  const float* gv  = (const float*)d_in[8];
  const float* bv_ = (const float*)d_in[9];
  const float* wq  = (const float*)d_in[10];
  const float* bqp = (const float*)d_in[11];
  const float* wk  = (const float*)d_in[12];
  const float* bkp = (const float*)d_in[13];
  const float* wv  = (const float*)d_in[14];
  const float* bvp = (const float*)d_in[15];
  const float* wp  = (const float*)d_in[16];
  const float* bpp = (const float*)d_in[17];
  const float* rph = (const float*)d_in[18];
  const float* rpw = (const float*)d_in[19];

  char* ws = (char*)d_ws;
  size_t off = 0;
  auto alloc = [&](size_t bytes) -> void* {
    void* p = ws + off; off += (bytes + 255) & ~(size_t)255; return p;
  };
  const size_t MROWS = (size_t)BATCH * NTOK;   // 12560
  short* Pq  = (short*)alloc(MROWS * DMODEL * 2);
  short* Pk  = (short*)alloc(MROWS * DMODEL * 2);
  short* Pv  = (short*)alloc(MROWS * DMODEL * 2);
  short* WqT = (short*)alloc((size_t)DMODEL * DMODEL * 2);
  short* WkT = (short*)alloc((size_t)DMODEL * DMODEL * 2);
  short* WvT = (short*)alloc((size_t)DMODEL * DMODEL * 2);
  short* WpT = (short*)alloc((size_t)DMODEL * DMODEL * 2);
  short* qhd = (short*)alloc(MROWS * DMODEL * 2 + 4096);
  short* khd = (short*)alloc(MROWS * DMODEL * 2 + 4096);
  short* vtg = (short*)alloc(MROWS * DMODEL * 2 + 8192);  // transposed V
  float* RelHt = (float*)alloc((size_t)BHCNT * 784 * 28 * 4);
  float* RelWt = (float*)alloc((size_t)BHCNT * 784 * 28 * 4);
  short* Afin = (short*)alloc(MROWS * DMODEL * 2);

  pool_ln_kernel<<<dim3(16 * 197), 192, 0, stream>>>(
      x, pqw, pkw, pvw, gq, bq_, gk, bk_, gv, bv_, Pq, Pk, Pv);
  trans_kernel<<<dim3(24, 24, 4), dim3(32, 8), 0, stream>>>(
      wq, wk, wv, wp, WqT, WkT, WvT, WpT);
  dim3 gg(99, 6);
  gemm2_kernel<<<gg, 256, 0, stream>>>(Pq, WqT, bqp, qhd, (int)MROWS, DMODEL, 1);
  gemm2_kernel<<<gg, 256, 0, stream>>>(Pk, WkT, bkp, khd, (int)MROWS, DMODEL, 1);
  gemm2_kernel<<<dim3(6, 99), 256, 0, stream>>>(WvT, Pv, bvp, vtg, DMODEL, (int)MROWS, 2);
  relbias_kernel<<<dim3(28, BHCNT, 2), 256, 0, stream>>>(qhd, rph, rpw, RelHt, RelWt);
  flash3_kernel<<<dim3(2496), 256, 0, stream>>>(qhd, khd, vtg, RelHt, RelWt, Afin);
  gemm2_kernel<<<gg, 256, 0, stream>>>(Afin, WpT, bpp, d_out, (int)MROWS, DMODEL, 0);
}

// Round 5
// 466.800 us; speedup vs baseline: 1.3523x; 1.3523x over previous
//
#include <hip/hip_runtime.h>
#include <stdint.h>

#define NUM_HEADS 12
#define HEAD_DIM  64
#define HWDIM     56
#define PHDIM     28
#define NTOK      785     // 28*28+1
#define NIN       3137    // 56*56+1
#define BATCH     16
#define DMODEL    768
#define BHCNT     192     // BATCH*NUM_HEADS

typedef __attribute__((ext_vector_type(8))) short bf16x8;
typedef __attribute__((ext_vector_type(4))) short s16x4;
typedef __attribute__((ext_vector_type(4))) float f32x4;
typedef __attribute__((ext_vector_type(2))) unsigned int u32x2;

static __device__ __forceinline__ float bf2f(short s) {
  unsigned u = ((unsigned)(unsigned short)s) << 16;
  float f; __builtin_memcpy(&f, &u, 4); return f;
}
static __device__ __forceinline__ short f2bf(float f) {
  unsigned u; __builtin_memcpy(&u, &f, 4);
  unsigned r = u + 0x7FFFu + ((u >> 16) & 1u);
  return (short)(r >> 16);
}

#if defined(__has_builtin)
#if __has_builtin(__builtin_amdgcn_global_load_lds)
#define HAVE_GLLDS 1
#endif
#endif

static __device__ __forceinline__ void gl_lds16(const short* g, short* l) {
#ifdef HAVE_GLLDS
  __builtin_amdgcn_global_load_lds(
      (const __attribute__((address_space(1))) void*)g,
      (__attribute__((address_space(3))) void*)l, 16, 0, 0);
#else
  int lane = threadIdx.x & 63;
  *(bf16x8*)(l + lane * 8) = *(const bf16x8*)g;
#endif
}

// ---------------------------------------------------------------- pool + LN
__global__ __launch_bounds__(192) void pool_ln_kernel(
    const float* __restrict__ x,
    const float* __restrict__ wq9, const float* __restrict__ wk9, const float* __restrict__ wv9,
    const float* __restrict__ gq, const float* __restrict__ bq,
    const float* __restrict__ gk, const float* __restrict__ bk,
    const float* __restrict__ gv, const float* __restrict__ bv,
    short* __restrict__ Pq, short* __restrict__ Pk, short* __restrict__ Pv)
{
  __shared__ __align__(16) float wt_s[3][9][64];   // [conv][tap][c]
  int tid = threadIdx.x;
  int blk = blockIdx.x;
  int b = blk / 197;
  int n0 = (blk - b * 197) * 4;

  for (int idx = tid; idx < 3 * 576; idx += 192) {
    int conv = idx / 576, rem = idx - conv * 576;
    int c = rem / 9, tap = rem - c * 9;
    const float* wsrc = (conv == 0) ? wq9 : (conv == 1) ? wk9 : wv9;
    wt_s[conv][tap][c] = wsrc[c * 9 + tap];
  }
  __syncthreads();

  int ch0 = tid * 4;
  int c4 = ch0 & 63;
  f32x4 g_q = *(const f32x4*)&gq[c4], b_q = *(const f32x4*)&bq[c4];
  f32x4 g_k = *(const f32x4*)&gk[c4], b_k = *(const f32x4*)&bk[c4];
  f32x4 g_v = *(const f32x4*)&gv[c4], b_v = *(const f32x4*)&bv[c4];

  for (int tt = 0; tt < 4; ++tt) {
    int n = n0 + tt;
    if (n >= NTOK) break;
    f32x4 aq = (f32x4){0.f, 0.f, 0.f, 0.f}, ak = aq, av = aq;
    if (n == 0) {
      f32x4 x4 = *(const f32x4*)&x[((size_t)b * NIN) * DMODEL + ch0];
      aq = ak = av = x4;
    } else {
      int s = n - 1;
      int i = s / PHDIM, j = s - i * PHDIM;
#pragma unroll
      for (int di = 0; di < 3; ++di) {
        int ii = 2 * i - 1 + di;
        if (ii < 0 || ii >= HWDIM) continue;
#pragma unroll
        for (int dj = 0; dj < 3; ++dj) {
          int jj = 2 * j - 1 + dj;
          if (jj < 0 || jj >= HWDIM) continue;
          f32x4 x4 = *(const f32x4*)&x[((size_t)b * NIN + 1 + ii * HWDIM + jj) * DMODEL + ch0];
          int tap = di * 3 + dj;
          f32x4 w0 = *(const f32x4*)&wt_s[0][tap][c4];
          f32x4 w1 = *(const f32x4*)&wt_s[1][tap][c4];
          f32x4 w2 = *(const f32x4*)&wt_s[2][tap][c4];
          aq += w0 * x4; ak += w1 * x4; av += w2 * x4;
        }
      }
    }
    size_t obase = ((size_t)b * NTOK + n) * DMODEL + ch0;
    {
      float sm = aq[0] + aq[1] + aq[2] + aq[3];
#pragma unroll
      for (int m = 1; m < 16; m <<= 1) sm += __shfl_xor(sm, m);
      float mn = sm * (1.f / 64.f);
      f32x4 d = aq - mn;
      float vs = d[0]*d[0] + d[1]*d[1] + d[2]*d[2] + d[3]*d[3];
#pragma unroll
      for (int m = 1; m < 16; m <<= 1) vs += __shfl_xor(vs, m);
      float rs = rsqrtf(vs * (1.f / 64.f) + 1e-5f);
      s16x4 o;
#pragma unroll
      for (int e = 0; e < 4; ++e) o[e] = f2bf(d[e] * rs * g_q[e] + b_q[e]);
      *(s16x4*)&Pq[obase] = o;
    }
    {
      float sm = ak[0] + ak[1] + ak[2] + ak[3];
#pragma unroll
      for (int m = 1; m < 16; m <<= 1) sm += __shfl_xor(sm, m);
      float mn = sm * (1.f / 64.f);
      f32x4 d = ak - mn;
      float vs = d[0]*d[0] + d[1]*d[1] + d[2]*d[2] + d[3]*d[3];
#pragma unroll
      for (int m = 1; m < 16; m <<= 1) vs += __shfl_xor(vs, m);
      float rs = rsqrtf(vs * (1.f / 64.f) + 1e-5f);
      s16x4 o;
#pragma unroll
      for (int e = 0; e < 4; ++e) o[e] = f2bf(d[e] * rs * g_k[e] + b_k[e]);
      *(s16x4*)&Pk[obase] = o;
    }
    {
      float sm = av[0] + av[1] + av[2] + av[3];
#pragma unroll
      for (int m = 1; m < 16; m <<= 1) sm += __shfl_xor(sm, m);
      float mn = sm * (1.f / 64.f);
      f32x4 d = av - mn;
      float vs = d[0]*d[0] + d[1]*d[1] + d[2]*d[2] + d[3]*d[3];
#pragma unroll
      for (int m = 1; m < 16; m <<= 1) vs += __shfl_xor(vs, m);
      float rs = rsqrtf(vs * (1.f / 64.f) + 1e-5f);
      s16x4 o;
#pragma unroll
      for (int e = 0; e < 4; ++e) o[e] = f2bf(d[e] * rs * g_v[e] + b_v[e]);
      *(s16x4*)&Pv[obase] = o;
    }
  }
}

// ------------------------------------------------- weight transpose fp32->bf16
__global__ __launch_bounds__(256) void trans_kernel(
    const float* __restrict__ s0, const float* __restrict__ s1,
    const float* __restrict__ s2, const float* __restrict__ s3,
    short* __restrict__ d0, short* __restrict__ d1,
    short* __restrict__ d2, short* __restrict__ d3)
{
  __shared__ float tile[32][33];
  int z = blockIdx.z;
  const float* s = (z == 0) ? s0 : (z == 1) ? s1 : (z == 2) ? s2 : s3;
  short* d = (z == 0) ? d0 : (z == 1) ? d1 : (z == 2) ? d2 : d3;
  int k0 = blockIdx.x * 32, n0 = blockIdx.y * 32;
  int tx = threadIdx.x, ty = threadIdx.y;   // 32 x 8
#pragma unroll
  for (int jj = 0; jj < 4; ++jj)
    tile[ty + jj * 8][tx] = s[(size_t)(k0 + ty + jj * 8) * DMODEL + n0 + tx];
  __syncthreads();
#pragma unroll
  for (int jj = 0; jj < 4; ++jj)
    d[(size_t)(n0 + ty + jj * 8) * DMODEL + k0 + tx] = f2bf(tile[tx][ty + jj * 8]);
}

// ------------------------------------------------------------- bf16 MFMA GEMM
// C[M,N] = A[M,768] @ Bt[N,768]^T + bias; dual-input via blockIdx.z
// mode0: fp32 row-major out; mode1: bf16 (B,12,785,64); mode2: bf16 transposed
__global__ __launch_bounds__(256) void gemm2_kernel(
    const short* __restrict__ A0, const short* __restrict__ Bt0,
    const float* __restrict__ bias0, void* __restrict__ out0,
    const short* __restrict__ A1, const short* __restrict__ Bt1,
    const float* __restrict__ bias1, void* __restrict__ out1,
    int M, int Nn, int mode)
{
  const int K = DMODEL;
  const short* A  = blockIdx.z ? A1 : A0;
  const short* Bt = blockIdx.z ? Bt1 : Bt0;
  const float* bias = blockIdx.z ? bias1 : bias0;
  void* outp = blockIdx.z ? out1 : out0;
  __shared__ short As[128 * 32];
  __shared__ short Bs[128 * 32];
  int tid = threadIdx.x;
  int wid = tid >> 6, lane = tid & 63;
  int lg = lane >> 4, lq = lane & 15;
  int wm = wid >> 1, wn = wid & 1;
  int rowbase = blockIdx.x * 128;
  int colbase = blockIdx.y * 128;

  f32x4 acc[4][4];
#pragma unroll
  for (int i = 0; i < 4; ++i)
#pragma unroll
    for (int j = 0; j < 4; ++j) acc[i][j] = (f32x4){0.f, 0.f, 0.f, 0.f};

  int srow = tid >> 2;
  int scol = (tid & 3) * 8;
  int ar0 = min(rowbase + srow, M - 1);
  int ar1 = min(rowbase + 64 + srow, M - 1);
  int br0 = min(colbase + srow, Nn - 1);
  int br1 = min(colbase + 64 + srow, Nn - 1);
  const short* Ag0 = A + (size_t)ar0 * K + scol;
  const short* Ag1 = A + (size_t)ar1 * K + scol;
  const short* Bg0 = Bt + (size_t)br0 * K + scol;
  const short* Bg1 = Bt + (size_t)br1 * K + scol;
  short* AsW0 = As + wid * 512;
  short* AsW1 = As + 2048 + wid * 512;
  short* BsW0 = Bs + wid * 512;
  short* BsW1 = Bs + 2048 + wid * 512;

  for (int kt = 0; kt < K; kt += 32) {
    __syncthreads();
    gl_lds16(Ag0 + kt, AsW0);
    gl_lds16(Ag1 + kt, AsW1);
    gl_lds16(Bg0 + kt, BsW0);
    gl_lds16(Bg1 + kt, BsW1);
    __syncthreads();
    bf16x8 aFrag[4], bFrag[4];
#pragma unroll
    for (int mi = 0; mi < 4; ++mi)
      aFrag[mi] = *(const bf16x8*)&As[(wm * 64 + mi * 16 + lq) * 32 + lg * 8];
#pragma unroll
    for (int ni = 0; ni < 4; ++ni)
      bFrag[ni] = *(const bf16x8*)&Bs[(wn * 64 + ni * 16 + lq) * 32 + lg * 8];
    __builtin_amdgcn_s_setprio(1);
#pragma unroll
    for (int mi = 0; mi < 4; ++mi)
#pragma unroll
      for (int ni = 0; ni < 4; ++ni)
        acc[mi][ni] = __builtin_amdgcn_mfma_f32_16x16x32_bf16(aFrag[mi], bFrag[ni], acc[mi][ni], 0, 0, 0);
    __builtin_amdgcn_s_setprio(0);
  }

#pragma unroll
  for (int mi = 0; mi < 4; ++mi) {
    int rowq = rowbase + wm * 64 + mi * 16 + lg * 4;
#pragma unroll
    for (int r = 0; r < 4; ++r) {
      int row = rowq + r;
      if (row < M) {
        if (mode == 2) {
          float bb = bias[row];
#pragma unroll
          for (int ni = 0; ni < 4; ++ni) {
            int col = colbase + wn * 64 + ni * 16 + lq;
            if (col < Nn) {
              int b = col / NTOK, n = col - b * NTOK;
              float v = acc[mi][ni][r] + bb;
              ((short*)outp)[((size_t)b * DMODEL + row) * NTOK + n] = f2bf(v);
            }
          }
        } else {
          int bb = row / NTOK;
          int nn = row - bb * NTOK;
#pragma unroll
          for (int ni = 0; ni < 4; ++ni) {
            int col = colbase + wn * 64 + ni * 16 + lq;
            float v = acc[mi][ni][r] + bias[col];
            if (mode == 0) {
              ((float*)outp)[(size_t)row * DMODEL + col] = v;
            } else {
              ((short*)outp)[(((size_t)(bb * NUM_HEADS + (col >> 6)) * NTOK + nn) << 6) + (col & 63)] = f2bf(v);
            }
          }
        }
      }
    }
  }
}

// -------------------------------------------------------- rel-pos bias tables
// transposed output: RelHt[bh][kk][qrow] (28 x 784 per bh)
__global__ __launch_bounds__(256) void relbias_kernel(
    const short* __restrict__ qh, const float* __restrict__ rph,
    const float* __restrict__ rpw, float* __restrict__ RelHt, float* __restrict__ RelWt)
{
  int line = blockIdx.x;   // i (mode0) or j (mode1)
  int bh = blockIdx.y;
  int mode = blockIdx.z;
  __shared__ __align__(16) float qt_s[28 * 68];
  __shared__ __align__(16) float rt_s[28 * 68];
  int tid = threadIdx.x;
  const float* rp = (mode == 0) ? rph : rpw;
  for (int idx = tid; idx < 28 * 64; idx += 256) {
    int rr = idx >> 6, c = idx & 63;
    int qi = (mode == 0) ? (1 + line * PHDIM + rr) : (1 + rr * PHDIM + line);
    qt_s[rr * 68 + c] = bf2f(qh[((size_t)bh * NTOK + qi) * HEAD_DIM + c]);
    rt_s[rr * 68 + c] = rp[(line - rr + 27) * HEAD_DIM + c];
  }
  __syncthreads();
  float* dst = (mode == 0) ? RelHt : RelWt;
  for (int o = tid; o < 784; o += 256) {
    int kk = o / PHDIM, rr = o - kk * PHDIM;
    const f32x4* qa = (const f32x4*)&qt_s[rr * 68];
    const f32x4* ra = (const f32x4*)&rt_s[kk * 68];
    f32x4 a4 = (f32x4){0.f, 0.f, 0.f, 0.f};
#pragma unroll
    for (int i = 0; i < 16; ++i) a4 += qa[i] * ra[i];
    float s = a4[0] + a4[1] + a4[2] + a4[3];
    int qrow = (mode == 0) ? (line * PHDIM + rr) : (rr * PHDIM + line);
    dst[((size_t)bh * PHDIM + kk) * 784 + qrow] = s;
  }
}

// ------------------------------------------------------------ flash attention
// swapped QK^T; K and V^T staged to LDS via global_load_lds (swizzled source,
// linear dest); all fragment reads quarter-wave conflict-free ds_read_b128.
__global__ __launch_bounds__(256) void flash4_kernel(
    const short* __restrict__ qh, const short* __restrict__ kh, const short* __restrict__ vtg,
    const float* __restrict__ RelHt, const float* __restrict__ RelWt,
    short* __restrict__ Afin)
{
  int id = blockIdx.x;
  int slot = id >> 3;
  int bh = (id & 7) * 24 + slot / 13;   // all 13 q-tiles of a bh on one XCD
  int qt = slot - (slot / 13) * 13;
  int qbase = qt * 64;
  int tid = threadIdx.x, wid = tid >> 6, lane = tid & 63;
  int lg = lane >> 4, lq = lane & 15;

  __shared__ __align__(16) short ks[64 * 64];      // K[key][d], d-chunks swizzled by key&7
  __shared__ __align__(16) short vt[64 * 64];      // V^T[d][key], key-chunks swizzled by d&7
  __shared__ __align__(16) short pbuf[4][16 * 64]; // per-wave P, 16B-slot swizzled
  __shared__ __align__(16) float relh_t[28][64];
  __shared__ __align__(16) float relw_t[28][64];
  __shared__ __align__(16) float axl[4][16];

  // stage rel tables transposed: col = q_local (covered by first loop barrier)
  for (int idx = tid; idx < 28 * 64; idx += 256) {
    int kk = idx >> 6, ql = idx & 63;
    int qi = qbase + ql;
    float rh = 0.f, rw = 0.f;
    if (qi >= 1 && qi < NTOK) {
      rh = RelHt[((size_t)bh * PHDIM + kk) * 784 + qi - 1];
      rw = RelWt[((size_t)bh * PHDIM + kk) * 784 + qi - 1];
    }
    relh_t[kk][ql] = rh; relw_t[kk][ql] = rw;
  }

  int qi0 = qbase + wid * 16 + lq;
  int qiq = min(qi0, NTOK - 1);
  const short* qrow = qh + ((size_t)bh * NTOK + qiq) * HEAD_DIM;
  bf16x8 bq0 = *(const bf16x8*)(qrow + lg * 8);
  bf16x8 bq1 = *(const bf16x8*)(qrow + 32 + lg * 8);

  float m_l = -3e30f, l_l = 0.f;
  f32x4 acc[4];
#pragma unroll
  for (int ch = 0; ch < 4; ++ch) acc[ch] = (f32x4){0.f, 0.f, 0.f, 0.f};

  const float scale = 0.125f;
  int q_local = wid * 16 + lq;
  const short* kbase = kh + (size_t)bh * NTOK * HEAD_DIM;
  const short* vbase = vtg + (size_t)bh * (size_t)HEAD_DIM * NTOK;

  // staging chunk ids (16B chunks; 512 per 8KB tile; 2 per thread)
  int c0 = tid, c1 = 256 + tid;
  int k_key0 = c0 >> 3, k_d20 = c0 & 7;
  int k_key1 = c1 >> 3, k_d21 = c1 & 7;
  int ksw0 = (k_d20 ^ (k_key0 & 7)) << 3;
  int ksw1 = (k_d21 ^ (k_key1 & 7)) << 3;

  for (int step = 0; step < 13; ++step) {
    int kvb = step * 64;
    __syncthreads();   // prior step's LDS reads done (also covers rel staging)
    {
      gl_lds16(kbase + (size_t)min(kvb + k_key0, NTOK - 1) * HEAD_DIM + ksw0,
               ks + wid * 512);
      gl_lds16(kbase + (size_t)min(kvb + k_key1, NTOK - 1) * HEAD_DIM + ksw1,
               ks + 2048 + wid * 512);
      gl_lds16(vbase + (size_t)k_key0 * NTOK + kvb + ksw0,
               vt + wid * 512);
      gl_lds16(vbase + (size_t)k_key1 * NTOK + kvb + ksw1,
               vt + 2048 + wid * 512);
    }
    __syncthreads();   // staged data visible

    float p[16];
#pragma unroll
    for (int kt = 0; kt < 4; ++kt) {
      int kl = kt * 16 + lq;
      const char* kp = (const char*)ks + kl * 128;
      int swz = kl & 7;
      bf16x8 aK0 = *(const bf16x8*)(kp + ((lg ^ swz) << 4));
      bf16x8 aK1 = *(const bf16x8*)(kp + (((lg + 4) ^ swz) << 4));
      f32x4 s = (f32x4){0.f, 0.f, 0.f, 0.f};
      __builtin_amdgcn_s_setprio(1);
      s = __builtin_amdgcn_mfma_f32_16x16x32_bf16(aK0, bq0, s, 0, 0, 0);
      s = __builtin_amdgcn_mfma_f32_16x16x32_bf16(aK1, bq1, s, 0, 0, 0);
      __builtin_amdgcn_s_setprio(0);
#pragma unroll
      for (int r = 0; r < 4; ++r) {
        int key = kvb + kt * 16 + lg * 4 + r;
        float v = s[r] * scale;
        if (key >= 1 && key < NTOK) {
          int km1 = key - 1;
          int ki = km1 / PHDIM, kj = km1 - ki * PHDIM;
          v += relh_t[ki][q_local] + relw_t[kj][q_local];
        }
        if (key >= NTOK) v = -3e30f;
        p[kt * 4 + r] = v;
      }
    }

    // softmax (q-row lane-local in columns; cross lane-groups via 2 shfls)
    float pm = p[0];
#pragma unroll
    for (int i = 1; i < 16; ++i) pm = fmaxf(pm, p[i]);
    pm = fmaxf(pm, __shfl_xor(pm, 16));
    pm = fmaxf(pm, __shfl_xor(pm, 32));
    if (!__all(pm - m_l <= 8.f)) {   // defer-rescale (T13)
      float mnew = fmaxf(m_l, pm);
      float alpha = __expf(m_l - mnew);
      m_l = mnew;
      l_l *= alpha;
      if (lg == 0) axl[wid][lq] = alpha;
      f32x4 av = *(const f32x4*)&axl[wid][lg * 4];
#pragma unroll
      for (int ch = 0; ch < 4; ++ch)
#pragma unroll
        for (int r = 0; r < 4; ++r) acc[ch][r] *= av[r];
    }
    float ps = 0.f;
#pragma unroll
    for (int i = 0; i < 16; ++i) { p[i] = __expf(p[i] - m_l); ps += p[i]; }
    ps += __shfl_xor(ps, 16);
    ps += __shfl_xor(ps, 32);
    l_l += ps;

    // pack P -> per-wave LDS (b64 writes, 16B-slot XOR swizzle)
    short* pw = (short*)pbuf[wid];
#pragma unroll
    for (int kt = 0; kt < 4; ++kt) {
      unsigned lo = ((unsigned)(unsigned short)f2bf(p[kt * 4 + 0])) |
                    ((unsigned)(unsigned short)f2bf(p[kt * 4 + 1]) << 16);
      unsigned hi = ((unsigned)(unsigned short)f2bf(p[kt * 4 + 2])) |
                    ((unsigned)(unsigned short)f2bf(p[kt * 4 + 3]) << 16);
      int byte = (lq * 128 + (kt * 16 + lg * 4) * 2) ^ ((lq & 7) << 4);
      u32x2 pk; pk[0] = lo; pk[1] = hi;
      *(u32x2*)((char*)pw + byte) = pk;
    }
    // PV: pa from pbuf, bv from swizzled vt
#pragma unroll
    for (int kc = 0; kc < 2; ++kc) {
      int pbyte = (lq * 128 + kc * 64 + lg * 16) ^ ((lq & 7) << 4);
      bf16x8 pa = *(const bf16x8*)((char*)pw + pbyte);
      __builtin_amdgcn_s_setprio(1);
#pragma unroll
      for (int ch = 0; ch < 4; ++ch) {
        int d = ch * 16 + lq;
        int vbyte = d * 128 + ((((kc << 2) + lg) ^ (lq & 7)) << 4);
        bf16x8 bv = *(const bf16x8*)((char*)vt + vbyte);
        acc[ch] = __builtin_amdgcn_mfma_f32_16x16x32_bf16(pa, bv, acc[ch], 0, 0, 0);
      }
      __builtin_amdgcn_s_setprio(0);
    }
  }

  if (lg == 0) axl[wid][lq] = l_l;
  f32x4 lv = *(const f32x4*)&axl[wid][lg * 4];
  int b = bh / NUM_HEADS, h = bh - b * NUM_HEADS;
#pragma unroll
  for (int r = 0; r < 4; ++r) {
    int qi = qbase + wid * 16 + lg * 4 + r;
    if (qi < NTOK) {
      float inv = 1.f / lv[r];
#pragma unroll
      for (int ch = 0; ch < 4; ++ch) {
        int d = ch * 16 + lq;
        float o = acc[ch][r] * inv + bf2f(qh[((size_t)bh * NTOK + qi) * HEAD_DIM + d]);
        Afin[((size_t)b * NTOK + qi) * DMODEL + h * HEAD_DIM + d] = f2bf(o);
      }
    }
  }
}

// ------------------------------------------------------------------- launcher
extern "C" void kernel_launch(void* const* d_in, const int* in_sizes, int n_in,
                              void* d_out, int out_size, void* d_ws, size_t ws_size,
                              hipStream_t stream)
{
  (void)in_sizes; (void)n_in; (void)out_size; (void)ws_size;
  const float* x   = (const float*)d_in[0];
  const float* pqw = (const float*)d_in[1];
  const float* pkw = (const float*)d_in[2];
  const float* pvw = (const float*)d_in[3];
  const float* gq  = (const float*)d_in[4];
  const float* bq_ = (const float*)d_in[5];
  const float* gk  = (const float*)d_in[6];
  const float* bk_ = (const float*)d_in[7];
  const float* gv  = (const float*)d_in[8];
  const float* bv_ = (const float*)d_in[9];
  const float* wq  = (const float*)d_in[10];
  const float* bqp = (const float*)d_in[11];
  const float* wk  = (const float*)d_in[12];
  const float* bkp = (const float*)d_in[13];
  const float* wv  = (const float*)d_in[14];
  const float* bvp = (const float*)d_in[15];
  const float* wp  = (const float*)d_in[16];
  const float* bpp = (const float*)d_in[17];
  const float* rph = (const float*)d_in[18];
  const float* rpw = (const float*)d_in[19];

  char* ws = (char*)d_ws;
  size_t off = 0;
  auto alloc = [&](size_t bytes) -> void* {
    void* p = ws + off; off += (bytes + 255) & ~(size_t)255; return p;
  };
  const size_t MROWS = (size_t)BATCH * NTOK;   // 12560
  short* Pq  = (short*)alloc(MROWS * DMODEL * 2);
  short* Pk  = (short*)alloc(MROWS * DMODEL * 2);
  short* Pv  = (short*)alloc(MROWS * DMODEL * 2);
  short* WqT = (short*)alloc((size_t)DMODEL * DMODEL * 2);
  short* WkT = (short*)alloc((size_t)DMODEL * DMODEL * 2);
  short* WvT = (short*)alloc((size_t)DMODEL * DMODEL * 2);
  short* WpT = (short*)alloc((size_t)DMODEL * DMODEL * 2);
  short* qhd = (short*)alloc(MROWS * DMODEL * 2 + 4096);
  short* khd = (short*)alloc(MROWS * DMODEL * 2 + 4096);
  short* vtg = (short*)alloc(MROWS * DMODEL * 2 + 8192);  // transposed V
  float* RelHt = (float*)alloc((size_t)BHCNT * 784 * 28 * 4);
  float* RelWt = (float*)alloc((size_t)BHCNT * 784 * 28 * 4);
  short* Afin = (short*)alloc(MROWS * DMODEL * 2);

  pool_ln_kernel<<<dim3(16 * 197), 192, 0, stream>>>(
      x, pqw, pkw, pvw, gq, bq_, gk, bk_, gv, bv_, Pq, Pk, Pv);
  trans_kernel<<<dim3(24, 24, 4), dim3(32, 8), 0, stream>>>(
      wq, wk, wv, wp, WqT, WkT, WvT, WpT);
  // fused Q & K projections (z=2)
  gemm2_kernel<<<dim3(99, 6, 2), 256, 0, stream>>>(
      Pq, WqT, bqp, qhd, Pk, WkT, bkp, khd, (int)MROWS, DMODEL, 1);
  // V^T projection
  gemm2_kernel<<<dim3(6, 99, 1), 256, 0, stream>>>(
      WvT, Pv, bvp, vtg, WvT, Pv, bvp, vtg, DMODEL, (int)MROWS, 2);
  relbias_kernel<<<dim3(28, BHCNT, 2), 256, 0, stream>>>(qhd, rph, rpw, RelHt, RelWt);
  flash4_kernel<<<dim3(2496), 256, 0, stream>>>(qhd, khd, vtg, RelHt, RelWt, Afin);
  gemm2_kernel<<<dim3(99, 6, 1), 256, 0, stream>>>(
      Afin, WpT, bpp, d_out, Afin, WpT, bpp, d_out, (int)MROWS, DMODEL, 0);
}

// Round 6
// 451.967 us; speedup vs baseline: 1.3967x; 1.0328x over previous
//
#include <hip/hip_runtime.h>
#include <stdint.h>

#define NUM_HEADS 12
#define HEAD_DIM  64
#define HWDIM     56
#define PHDIM     28
#define NTOK      785     // 28*28+1
#define NIN       3137    // 56*56+1
#define BATCH     16
#define DMODEL    768
#define BHCNT     192     // BATCH*NUM_HEADS
#define LOG2E     1.44269504f

typedef __attribute__((ext_vector_type(8))) short bf16x8;
typedef __attribute__((ext_vector_type(4))) short s16x4;
typedef __attribute__((ext_vector_type(4))) float f32x4;

static __device__ __forceinline__ float bf2f(short s) {
  unsigned u = ((unsigned)(unsigned short)s) << 16;
  float f; __builtin_memcpy(&f, &u, 4); return f;
}
static __device__ __forceinline__ short f2bf(float f) {
  unsigned u; __builtin_memcpy(&u, &f, 4);
  unsigned r = u + 0x7FFFu + ((u >> 16) & 1u);
  return (short)(r >> 16);
}
static __device__ __forceinline__ float fexp2(float x) {
#if defined(__has_builtin)
#if __has_builtin(__builtin_amdgcn_exp2f)
  return __builtin_amdgcn_exp2f(x);
#else
  return exp2f(x);
#endif
#else
  return exp2f(x);
#endif
}

#if defined(__has_builtin)
#if __has_builtin(__builtin_amdgcn_global_load_lds)
#define HAVE_GLLDS 1
#endif
#endif

static __device__ __forceinline__ void gl_lds16(const short* g, short* l) {
#ifdef HAVE_GLLDS
  __builtin_amdgcn_global_load_lds(
      (const __attribute__((address_space(1))) void*)g,
      (__attribute__((address_space(3))) void*)l, 16, 0, 0);
#else
  int lane = threadIdx.x & 63;
  *(bf16x8*)(l + lane * 8) = *(const bf16x8*)g;
#endif
}

// ---------------------------------------------------------------- pool + LN
__global__ __launch_bounds__(192) void pool_ln_kernel(
    const float* __restrict__ x,
    const float* __restrict__ wq9, const float* __restrict__ wk9, const float* __restrict__ wv9,
    const float* __restrict__ gq, const float* __restrict__ bq,
    const float* __restrict__ gk, const float* __restrict__ bk,
    const float* __restrict__ gv, const float* __restrict__ bv,
    short* __restrict__ Pq, short* __restrict__ Pk, short* __restrict__ Pv)
{
  __shared__ __align__(16) float wt_s[3][9][64];   // [conv][tap][c]
  int tid = threadIdx.x;
  int blk = blockIdx.x;
  int b = blk / 197;
  int n0 = (blk - b * 197) * 4;

  for (int idx = tid; idx < 3 * 576; idx += 192) {
    int conv = idx / 576, rem = idx - conv * 576;
    int c = rem / 9, tap = rem - c * 9;
    const float* wsrc = (conv == 0) ? wq9 : (conv == 1) ? wk9 : wv9;
    wt_s[conv][tap][c] = wsrc[c * 9 + tap];
  }
  __syncthreads();

  int ch0 = tid * 4;
  int c4 = ch0 & 63;
  f32x4 g_q = *(const f32x4*)&gq[c4], b_q = *(const f32x4*)&bq[c4];
  f32x4 g_k = *(const f32x4*)&gk[c4], b_k = *(const f32x4*)&bk[c4];
  f32x4 g_v = *(const f32x4*)&gv[c4], b_v = *(const f32x4*)&bv[c4];

  for (int tt = 0; tt < 4; ++tt) {
    int n = n0 + tt;
    if (n >= NTOK) break;
    f32x4 aq = (f32x4){0.f, 0.f, 0.f, 0.f}, ak = aq, av = aq;
    if (n == 0) {
      f32x4 x4 = *(const f32x4*)&x[((size_t)b * NIN) * DMODEL + ch0];
      aq = ak = av = x4;
    } else {
      int s = n - 1;
      int i = s / PHDIM, j = s - i * PHDIM;
#pragma unroll
      for (int di = 0; di < 3; ++di) {
        int ii = 2 * i - 1 + di;
        if (ii < 0 || ii >= HWDIM) continue;
#pragma unroll
        for (int dj = 0; dj < 3; ++dj) {
          int jj = 2 * j - 1 + dj;
          if (jj < 0 || jj >= HWDIM) continue;
          f32x4 x4 = *(const f32x4*)&x[((size_t)b * NIN + 1 + ii * HWDIM + jj) * DMODEL + ch0];
          int tap = di * 3 + dj;
          f32x4 w0 = *(const f32x4*)&wt_s[0][tap][c4];
          f32x4 w1 = *(const f32x4*)&wt_s[1][tap][c4];
          f32x4 w2 = *(const f32x4*)&wt_s[2][tap][c4];
          aq += w0 * x4; ak += w1 * x4; av += w2 * x4;
        }
      }
    }
    size_t obase = ((size_t)b * NTOK + n) * DMODEL + ch0;
    {
      float sm = aq[0] + aq[1] + aq[2] + aq[3];
#pragma unroll
      for (int m = 1; m < 16; m <<= 1) sm += __shfl_xor(sm, m);
      float mn = sm * (1.f / 64.f);
      f32x4 d = aq - mn;
      float vs = d[0]*d[0] + d[1]*d[1] + d[2]*d[2] + d[3]*d[3];
#pragma unroll
      for (int m = 1; m < 16; m <<= 1) vs += __shfl_xor(vs, m);
      float rs = rsqrtf(vs * (1.f / 64.f) + 1e-5f);
      s16x4 o;
#pragma unroll
      for (int e = 0; e < 4; ++e) o[e] = f2bf(d[e] * rs * g_q[e] + b_q[e]);
      *(s16x4*)&Pq[obase] = o;
    }
    {
      float sm = ak[0] + ak[1] + ak[2] + ak[3];
#pragma unroll
      for (int m = 1; m < 16; m <<= 1) sm += __shfl_xor(sm, m);
      float mn = sm * (1.f / 64.f);
      f32x4 d = ak - mn;
      float vs = d[0]*d[0] + d[1]*d[1] + d[2]*d[2] + d[3]*d[3];
#pragma unroll
      for (int m = 1; m < 16; m <<= 1) vs += __shfl_xor(vs, m);
      float rs = rsqrtf(vs * (1.f / 64.f) + 1e-5f);
      s16x4 o;
#pragma unroll
      for (int e = 0; e < 4; ++e) o[e] = f2bf(d[e] * rs * g_k[e] + b_k[e]);
      *(s16x4*)&Pk[obase] = o;
    }
    {
      float sm = av[0] + av[1] + av[2] + av[3];
#pragma unroll
      for (int m = 1; m < 16; m <<= 1) sm += __shfl_xor(sm, m);
      float mn = sm * (1.f / 64.f);
      f32x4 d = av - mn;
      float vs = d[0]*d[0] + d[1]*d[1] + d[2]*d[2] + d[3]*d[3];
#pragma unroll
      for (int m = 1; m < 16; m <<= 1) vs += __shfl_xor(vs, m);
      float rs = rsqrtf(vs * (1.f / 64.f) + 1e-5f);
      s16x4 o;
#pragma unroll
      for (int e = 0; e < 4; ++e) o[e] = f2bf(d[e] * rs * g_v[e] + b_v[e]);
      *(s16x4*)&Pv[obase] = o;
    }
  }
}

// ------------------------------------------------- weight transpose fp32->bf16
__global__ __launch_bounds__(256) void trans_kernel(
    const float* __restrict__ s0, const float* __restrict__ s1,
    const float* __restrict__ s2, const float* __restrict__ s3,
    short* __restrict__ d0, short* __restrict__ d1,
    short* __restrict__ d2, short* __restrict__ d3)
{
  __shared__ float tile[32][33];
  int z = blockIdx.z;
  const float* s = (z == 0) ? s0 : (z == 1) ? s1 : (z == 2) ? s2 : s3;
  short* d = (z == 0) ? d0 : (z == 1) ? d1 : (z == 2) ? d2 : d3;
  int k0 = blockIdx.x * 32, n0 = blockIdx.y * 32;
  int tx = threadIdx.x, ty = threadIdx.y;   // 32 x 8
#pragma unroll
  for (int jj = 0; jj < 4; ++jj)
    tile[ty + jj * 8][tx] = s[(size_t)(k0 + ty + jj * 8) * DMODEL + n0 + tx];
  __syncthreads();
#pragma unroll
  for (int jj = 0; jj < 4; ++jj)
    d[(size_t)(n0 + ty + jj * 8) * DMODEL + k0 + tx] = f2bf(tile[tx][ty + jj * 8]);
}

// ------------------------------------------------------------- bf16 MFMA GEMM
__global__ __launch_bounds__(256) void gemm2_kernel(
    const short* __restrict__ A0, const short* __restrict__ Bt0,
    const float* __restrict__ bias0, void* __restrict__ out0,
    const short* __restrict__ A1, const short* __restrict__ Bt1,
    const float* __restrict__ bias1, void* __restrict__ out1,
    int M, int Nn, int mode)
{
  const int K = DMODEL;
  const short* A  = blockIdx.z ? A1 : A0;
  const short* Bt = blockIdx.z ? Bt1 : Bt0;
  const float* bias = blockIdx.z ? bias1 : bias0;
  void* outp = blockIdx.z ? out1 : out0;
  __shared__ short As[128 * 32];
  __shared__ short Bs[128 * 32];
  int tid = threadIdx.x;
  int wid = tid >> 6, lane = tid & 63;
  int lg = lane >> 4, lq = lane & 15;
  int wm = wid >> 1, wn = wid & 1;
  int rowbase = blockIdx.x * 128;
  int colbase = blockIdx.y * 128;

  f32x4 acc[4][4];
#pragma unroll
  for (int i = 0; i < 4; ++i)
#pragma unroll
    for (int j = 0; j < 4; ++j) acc[i][j] = (f32x4){0.f, 0.f, 0.f, 0.f};

  int srow = tid >> 2;
  int scol = (tid & 3) * 8;
  int ar0 = min(rowbase + srow, M - 1);
  int ar1 = min(rowbase + 64 + srow, M - 1);
  int br0 = min(colbase + srow, Nn - 1);
  int br1 = min(colbase + 64 + srow, Nn - 1);
  const short* Ag0 = A + (size_t)ar0 * K + scol;
  const short* Ag1 = A + (size_t)ar1 * K + scol;
  const short* Bg0 = Bt + (size_t)br0 * K + scol;
  const short* Bg1 = Bt + (size_t)br1 * K + scol;
  short* AsW0 = As + wid * 512;
  short* AsW1 = As + 2048 + wid * 512;
  short* BsW0 = Bs + wid * 512;
  short* BsW1 = Bs + 2048 + wid * 512;

  for (int kt = 0; kt < K; kt += 32) {
    __syncthreads();
    gl_lds16(Ag0 + kt, AsW0);
    gl_lds16(Ag1 + kt, AsW1);
    gl_lds16(Bg0 + kt, BsW0);
    gl_lds16(Bg1 + kt, BsW1);
    __syncthreads();
    bf16x8 aFrag[4], bFrag[4];
#pragma unroll
    for (int mi = 0; mi < 4; ++mi)
      aFrag[mi] = *(const bf16x8*)&As[(wm * 64 + mi * 16 + lq) * 32 + lg * 8];
#pragma unroll
    for (int ni = 0; ni < 4; ++ni)
      bFrag[ni] = *(const bf16x8*)&Bs[(wn * 64 + ni * 16 + lq) * 32 + lg * 8];
    __builtin_amdgcn_s_setprio(1);
#pragma unroll
    for (int mi = 0; mi < 4; ++mi)
#pragma unroll
      for (int ni = 0; ni < 4; ++ni)
        acc[mi][ni] = __builtin_amdgcn_mfma_f32_16x16x32_bf16(aFrag[mi], bFrag[ni], acc[mi][ni], 0, 0, 0);
    __builtin_amdgcn_s_setprio(0);
  }

#pragma unroll
  for (int mi = 0; mi < 4; ++mi) {
    int rowq = rowbase + wm * 64 + mi * 16 + lg * 4;
#pragma unroll
    for (int r = 0; r < 4; ++r) {
      int row = rowq + r;
      if (row < M) {
        if (mode == 2) {
          float bb = bias[row];
#pragma unroll
          for (int ni = 0; ni < 4; ++ni) {
            int col = colbase + wn * 64 + ni * 16 + lq;
            if (col < Nn) {
              int b = col / NTOK, n = col - b * NTOK;
              float v = acc[mi][ni][r] + bb;
              ((short*)outp)[((size_t)b * DMODEL + row) * NTOK + n] = f2bf(v);
            }
          }
        } else {
          int bb = row / NTOK;
          int nn = row - bb * NTOK;
#pragma unroll
          for (int ni = 0; ni < 4; ++ni) {
            int col = colbase + wn * 64 + ni * 16 + lq;
            float v = acc[mi][ni][r] + bias[col];
            if (mode == 0) {
              ((float*)outp)[(size_t)row * DMODEL + col] = v;
            } else {
              ((short*)outp)[(((size_t)(bb * NUM_HEADS + (col >> 6)) * NTOK + nn) << 6) + (col & 63)] = f2bf(v);
            }
          }
        }
      }
    }
  }
}

// -------------------------------------------------------- rel-pos bias tables
// transposed bf16 output, pre-scaled by log2e: RelHt[bh][kk][qrow]
__global__ __launch_bounds__(256) void relbias_kernel(
    const short* __restrict__ qh, const float* __restrict__ rph,
    const float* __restrict__ rpw, short* __restrict__ RelHt, short* __restrict__ RelWt)
{
  int line = blockIdx.x;   // i (mode0) or j (mode1)
  int bh = blockIdx.y;
  int mode = blockIdx.z;
  __shared__ __align__(16) float qt_s[28 * 68];
  __shared__ __align__(16) float rt_s[28 * 68];
  int tid = threadIdx.x;
  const float* rp = (mode == 0) ? rph : rpw;
  for (int idx = tid; idx < 28 * 64; idx += 256) {
    int rr = idx >> 6, c = idx & 63;
    int qi = (mode == 0) ? (1 + line * PHDIM + rr) : (1 + rr * PHDIM + line);
    qt_s[rr * 68 + c] = bf2f(qh[((size_t)bh * NTOK + qi) * HEAD_DIM + c]);
    rt_s[rr * 68 + c] = rp[(line - rr + 27) * HEAD_DIM + c];
  }
  __syncthreads();
  short* dst = (mode == 0) ? RelHt : RelWt;
  for (int o = tid; o < 784; o += 256) {
    int kk = o / PHDIM, rr = o - kk * PHDIM;
    const f32x4* qa = (const f32x4*)&qt_s[rr * 68];
    const f32x4* ra = (const f32x4*)&rt_s[kk * 68];
    f32x4 a4 = (f32x4){0.f, 0.f, 0.f, 0.f};
#pragma unroll
    for (int i = 0; i < 16; ++i) a4 += qa[i] * ra[i];
    float s = (a4[0] + a4[1] + a4[2] + a4[3]) * LOG2E;
    int qrow = (mode == 0) ? (line * PHDIM + rr) : (rr * PHDIM + line);
    dst[((size_t)bh * PHDIM + kk) * 784 + qrow] = f2bf(s);
  }
}

// ------------------------------------------------------------ flash attention
// swapped QK^T with sigma-permuted K rows: lane owns 16 CONSECUTIVE keys
// [16*lg, 16*lg+16) for its q-row -> PV A-fragments are lane-local (no LDS P).
__global__ __launch_bounds__(256) void flash5_kernel(
    const short* __restrict__ qh, const short* __restrict__ kh, const short* __restrict__ vtg,
    const short* __restrict__ RelHt, const short* __restrict__ RelWt,
    short* __restrict__ Afin)
{
  int id = blockIdx.x;
  int slot = id >> 3;
  int bh = (id & 7) * 24 + slot / 13;   // all 13 q-tiles of a bh on one XCD
  int qt = slot - (slot / 13) * 13;
  int qbase = qt * 64;
  int tid = threadIdx.x, wid = tid >> 6, lane = tid & 63;
  int lg = lane >> 4, lq = lane & 15;

  __shared__ __align__(16) short ks[64 * 64];      // sigma-permuted K rows, chunk-swizzled
  __shared__ __align__(16) short vt[64 * 64];      // V^T[d][key], key-chunks swizzled by d&7
  __shared__ __align__(16) float relh_t[28][64];   // [ki][q_local], log2e-scaled
  __shared__ __align__(16) float relw_t[28][64];
  __shared__ __align__(16) float axl[4][16];

  for (int idx = tid; idx < 28 * 64; idx += 256) {
    int kk = idx >> 6, ql = idx & 63;
    int qi = qbase + ql;
    float rh = 0.f, rw = 0.f;
    if (qi >= 1 && qi < NTOK) {
      rh = bf2f(RelHt[((size_t)bh * PHDIM + kk) * 784 + qi - 1]);
      rw = bf2f(RelWt[((size_t)bh * PHDIM + kk) * 784 + qi - 1]);
    }
    relh_t[kk][ql] = rh; relw_t[kk][ql] = rw;
  }

  int qi0 = qbase + wid * 16 + lq;
  int qiq = min(qi0, NTOK - 1);
  const short* qrow = qh + ((size_t)bh * NTOK + qiq) * HEAD_DIM;
  bf16x8 bq0 = *(const bf16x8*)(qrow + lg * 8);
  bf16x8 bq1 = *(const bf16x8*)(qrow + 32 + lg * 8);

  float m_l = -3e30f, l_l = 0.f;
  f32x4 acc[4];
#pragma unroll
  for (int ch = 0; ch < 4; ++ch) acc[ch] = (f32x4){0.f, 0.f, 0.f, 0.f};

  const float scale2 = 0.125f * LOG2E;
  int q_local = wid * 16 + lq;
  const short* kbase = kh + (size_t)bh * NTOK * HEAD_DIM;
  const short* vbase = vtg + (size_t)bh * (size_t)HEAD_DIM * NTOK;

  // staging geometry: chunk c -> LDS row rr=c>>3, slot j=c&7 (2 chunks/thread)
  int c0 = tid, c1 = 256 + tid;
  int rr0 = c0 >> 3, j0 = c0 & 7;
  int rr1 = c1 >> 3, j1 = c1 & 7;
  // K: sigma(rr) = 16*((rr&15)>>2) + 4*(rr>>4) + (rr&3); slot j holds d-chunk j^(rr&7)
  int koff0 = ((rr0 & 15) >> 2) * 16 + (rr0 >> 4) * 4 + (rr0 & 3);
  int koff1 = ((rr1 & 15) >> 2) * 16 + (rr1 >> 4) * 4 + (rr1 & 3);
  int ksw0 = (j0 ^ (rr0 & 7)) << 3;
  int ksw1 = (j1 ^ (rr1 & 7)) << 3;
  // V: row d = rr, slot j holds key-chunk j^(d&7)
  int vsw0 = (j0 ^ (rr0 & 7)) << 3;
  int vsw1 = (j1 ^ (rr1 & 7)) << 3;
  const short* vsrc0 = vbase + (size_t)rr0 * NTOK + vsw0;
  const short* vsrc1 = vbase + (size_t)rr1 * NTOK + vsw1;

  auto step_body = [&](int kvb, bool first, bool last) __attribute__((always_inline)) {
    __syncthreads();   // prior step's LDS reads done (also covers rel staging)
    gl_lds16(kbase + (size_t)min(kvb + koff0, NTOK - 1) * HEAD_DIM + ksw0, ks + wid * 512);
    gl_lds16(kbase + (size_t)min(kvb + koff1, NTOK - 1) * HEAD_DIM + ksw1, ks + 2048 + wid * 512);
    gl_lds16(vsrc0 + kvb, vt + wid * 512);
    gl_lds16(vsrc1 + kvb, vt + 2048 + wid * 512);
    __syncthreads();   // staged data visible

    // rel index walk: lane's keys are base..base+15 consecutive
    int base = kvb + 16 * lg;
    int km1 = base - 1;
    int t = max(km1, 0);
    int ki = t / PHDIM;
    int kj = t - ki * PHDIM;
    if (km1 < 0) kj = -1;

    float p[16];
#pragma unroll
    for (int kt = 0; kt < 4; ++kt) {
      int kl = kt * 16 + lq;
      const char* kp = (const char*)ks + kl * 128;
      int swz = kl & 7;
      bf16x8 aK0 = *(const bf16x8*)(kp + ((lg ^ swz) << 4));
      bf16x8 aK1 = *(const bf16x8*)(kp + (((lg + 4) ^ swz) << 4));
      f32x4 s = (f32x4){0.f, 0.f, 0.f, 0.f};
      __builtin_amdgcn_s_setprio(1);
      s = __builtin_amdgcn_mfma_f32_16x16x32_bf16(aK0, bq0, s, 0, 0, 0);
      s = __builtin_amdgcn_mfma_f32_16x16x32_bf16(aK1, bq1, s, 0, 0, 0);
      __builtin_amdgcn_s_setprio(0);
#pragma unroll
      for (int r = 0; r < 4; ++r) {
        int i = kt * 4 + r;
        float v = s[r] * scale2;
        if (first) {
          int key = base + i;
          if (key >= 1) v += relh_t[ki][q_local] + relw_t[kj][q_local];
        } else if (last) {
          int key = base + i;
          v += relh_t[ki][q_local] + relw_t[kj][q_local];
          if (key >= NTOK) v = -3e30f;
        } else {
          v += relh_t[ki][q_local] + relw_t[kj][q_local];
        }
        p[i] = v;
        // advance (ki,kj) to next key
        ++kj;
        if (kj == PHDIM) { kj = 0; ++ki; }
      }
    }

    // softmax over lane's 16 + cross lane-group (same q) via 2 shfls
    float pm = p[0];
#pragma unroll
    for (int i = 1; i < 16; ++i) pm = fmaxf(pm, p[i]);
    pm = fmaxf(pm, __shfl_xor(pm, 16));
    pm = fmaxf(pm, __shfl_xor(pm, 32));
    if (!__all(pm - m_l <= 11.5f)) {   // defer-rescale (T13, log2 units)
      float mnew = fmaxf(m_l, pm);
      float alpha = fexp2(m_l - mnew);
      m_l = mnew;
      l_l *= alpha;
      if (lg == 0) axl[wid][lq] = alpha;
      f32x4 av = *(const f32x4*)&axl[wid][lg * 4];
#pragma unroll
      for (int ch = 0; ch < 4; ++ch)
#pragma unroll
        for (int r = 0; r < 4; ++r) acc[ch][r] *= av[r];
    }
    float ps = 0.f;
#pragma unroll
    for (int i = 0; i < 16; ++i) { p[i] = fexp2(p[i] - m_l); ps += p[i]; }
    ps += __shfl_xor(ps, 16);
    ps += __shfl_xor(ps, 32);
    l_l += ps;

    // pack lane-local P -> bf16 fragments (truncating)
    bf16x8 pa0, pa1;
#pragma unroll
    for (int j = 0; j < 4; ++j) {
      unsigned u0, u1, v0, v1;
      __builtin_memcpy(&u0, &p[2 * j], 4);
      __builtin_memcpy(&u1, &p[2 * j + 1], 4);
      __builtin_memcpy(&v0, &p[8 + 2 * j], 4);
      __builtin_memcpy(&v1, &p[8 + 2 * j + 1], 4);
      ((unsigned*)&pa0)[j] = (u0 >> 16) | (u1 & 0xFFFF0000u);
      ((unsigned*)&pa1)[j] = (v0 >> 16) | (v1 & 0xFFFF0000u);
    }
    // PV: A = lane-local P, B = V^T from LDS (k-order sigma' = 16lg+8kc+e)
    __builtin_amdgcn_s_setprio(1);
#pragma unroll
    for (int ch = 0; ch < 4; ++ch) {
      int d = ch * 16 + lq;
      const char* vrow = (const char*)vt + d * 128;
      int swz = lq & 7;
      bf16x8 bv0 = *(const bf16x8*)(vrow + (((2 * lg + 0) ^ swz) << 4));
      bf16x8 bv1 = *(const bf16x8*)(vrow + (((2 * lg + 1) ^ swz) << 4));
      acc[ch] = __builtin_amdgcn_mfma_f32_16x16x32_bf16(pa0, bv0, acc[ch], 0, 0, 0);
      acc[ch] = __builtin_amdgcn_mfma_f32_16x16x32_bf16(pa1, bv1, acc[ch], 0, 0, 0);
    }
    __builtin_amdgcn_s_setprio(0);
  };

  step_body(0, true, false);
  for (int step = 1; step < 12; ++step) step_body(step * 64, false, false);
  step_body(12 * 64, false, true);

  if (lg == 0) axl[wid][lq] = l_l;
  f32x4 lv = *(const f32x4*)&axl[wid][lg * 4];
  int b = bh / NUM_HEADS, h = bh - b * NUM_HEADS;
#pragma unroll
  for (int r = 0; r < 4; ++r) {
    int qi = qbase + wid * 16 + lg * 4 + r;
    if (qi < NTOK) {
      float inv = 1.f / lv[r];
#pragma unroll
      for (int ch = 0; ch < 4; ++ch) {
        int d = ch * 16 + lq;
        float o = acc[ch][r] * inv + bf2f(qh[((size_t)bh * NTOK + qi) * HEAD_DIM + d]);
        Afin[((size_t)b * NTOK + qi) * DMODEL + h * HEAD_DIM + d] = f2bf(o);
      }
    }
  }
}

// ------------------------------------------------------------------- launcher
extern "C" void kernel_launch(void* const* d_in, const int* in_sizes, int n_in,
                              void* d_out, int out_size, void* d_ws, size_t ws_size,
                              hipStream_t stream)
{
  (void)in_sizes; (void)n_in; (void)out_size; (void)ws_size;
  const float* x   = (const float*)d_in[0];
  const float* pqw = (const float*)d_in[1];
  const float* pkw = (const float*)d_in[2];
  const float* pvw = (const float*)d_in[3];
  const float* gq  = (const float*)d_in[4];
  const float* bq_ = (const float*)d_in[5];
  const float* gk  = (const float*)d_in[6];
  const float* bk_ = (const float*)d_in[7];
  const float* gv  = (const float*)d_in[8];
  const float* bv_ = (const float*)d_in[9];
  const float* wq  = (const float*)d_in[10];
  const float* bqp = (const float*)d_in[11];
  const float* wk  = (const float*)d_in[12];
  const float* bkp = (const float*)d_in[13];
  const float* wv  = (const float*)d_in[14];
  const float* bvp = (const float*)d_in[15];
  const float* wp  = (const float*)d_in[16];
  const float* bpp = (const float*)d_in[17];
  const float* rph = (const float*)d_in[18];
  const float* rpw = (const float*)d_in[19];

  char* ws = (char*)d_ws;
  size_t off = 0;
  auto alloc = [&](size_t bytes) -> void* {
    void* p = ws + off; off += (bytes + 255) & ~(size_t)255; return p;
  };
  const size_t MROWS = (size_t)BATCH * NTOK;   // 12560
  short* Pq  = (short*)alloc(MROWS * DMODEL * 2);
  short* Pk  = (short*)alloc(MROWS * DMODEL * 2);
  short* Pv  = (short*)alloc(MROWS * DMODEL * 2);
  short* WqT = (short*)alloc((size_t)DMODEL * DMODEL * 2);
  short* WkT = (short*)alloc((size_t)DMODEL * DMODEL * 2);
  short* WvT = (short*)alloc((size_t)DMODEL * DMODEL * 2);
  short* WpT = (short*)alloc((size_t)DMODEL * DMODEL * 2);
  short* qhd = (short*)alloc(MROWS * DMODEL * 2 + 4096);
  short* khd = (short*)alloc(MROWS * DMODEL * 2 + 4096);
  short* vtg = (short*)alloc(MROWS * DMODEL * 2 + 8192);  // transposed V
  short* RelHt = (short*)alloc((size_t)BHCNT * 784 * 28 * 2);
  short* RelWt = (short*)alloc((size_t)BHCNT * 784 * 28 * 2);
  short* Afin = (short*)alloc(MROWS * DMODEL * 2);

  pool_ln_kernel<<<dim3(16 * 197), 192, 0, stream>>>(
      x, pqw, pkw, pvw, gq, bq_, gk, bk_, gv, bv_, Pq, Pk, Pv);
  trans_kernel<<<dim3(24, 24, 4), dim3(32, 8), 0, stream>>>(
      wq, wk, wv, wp, WqT, WkT, WvT, WpT);
  gemm2_kernel<<<dim3(99, 6, 2), 256, 0, stream>>>(
      Pq, WqT, bqp, qhd, Pk, WkT, bkp, khd, (int)MROWS, DMODEL, 1);
  gemm2_kernel<<<dim3(6, 99, 1), 256, 0, stream>>>(
      WvT, Pv, bvp, vtg, WvT, Pv, bvp, vtg, DMODEL, (int)MROWS, 2);
  relbias_kernel<<<dim3(28, BHCNT, 2), 256, 0, stream>>>(qhd, rph, rpw, RelHt, RelWt);
  flash5_kernel<<<dim3(2496), 256, 0, stream>>>(qhd, khd, vtg, RelHt, RelWt, Afin);
  gemm2_kernel<<<dim3(99, 6, 1), 256, 0, stream>>>(
      Afin, WpT, bpp, d_out, Afin, WpT, bpp, d_out, (int)MROWS, DMODEL, 0);
}

// Round 7
// 397.673 us; speedup vs baseline: 1.5873x; 1.1365x over previous
//
#include <hip/hip_runtime.h>
#include <stdint.h>

#define NUM_HEADS 12
#define HEAD_DIM  64
#define HWDIM     56
#define PHDIM     28
#define NTOK      785     // 28*28+1
#define NIN       3137    // 56*56+1
#define BATCH     16
#define DMODEL    768
#define BHCNT     192     // BATCH*NUM_HEADS
#define LOG2E     1.44269504f

typedef __attribute__((ext_vector_type(8))) short bf16x8;
typedef __attribute__((ext_vector_type(4))) short s16x4;
typedef __attribute__((ext_vector_type(4))) float f32x4;

static __device__ __forceinline__ float bf2f(short s) {
  unsigned u = ((unsigned)(unsigned short)s) << 16;
  float f; __builtin_memcpy(&f, &u, 4); return f;
}
static __device__ __forceinline__ short f2bf(float f) {
  unsigned u; __builtin_memcpy(&u, &f, 4);
  unsigned r = u + 0x7FFFu + ((u >> 16) & 1u);
  return (short)(r >> 16);
}
static __device__ __forceinline__ float fexp2(float x) {
#if defined(__has_builtin)
#if __has_builtin(__builtin_amdgcn_exp2f)
  return __builtin_amdgcn_exp2f(x);
#else
  return exp2f(x);
#endif
#else
  return exp2f(x);
#endif
}

// bijective XCD chunking (m204): hardware round-robins blockIdx%8 across XCDs;
// map so each XCD owns a CONTIGUOUS logical range.
static __device__ __forceinline__ int xcd_chunk(int orig, int nwg) {
  int xcd = orig & 7;
  int within = orig >> 3;
  int q = nwg >> 3, r = nwg & 7;
  int base = (xcd < r) ? xcd * (q + 1) : r * (q + 1) + (xcd - r) * q;
  return base + within;
}

#if defined(__has_builtin)
#if __has_builtin(__builtin_amdgcn_global_load_lds)
#define HAVE_GLLDS 1
#endif
#endif

static __device__ __forceinline__ void gl_lds16(const short* g, short* l) {
#ifdef HAVE_GLLDS
  __builtin_amdgcn_global_load_lds(
      (const __attribute__((address_space(1))) void*)g,
      (__attribute__((address_space(3))) void*)l, 16, 0, 0);
#else
  int lane = threadIdx.x & 63;
  *(bf16x8*)(l + lane * 8) = *(const bf16x8*)g;
#endif
}

// ---------------------------------------------------------------- pool + LN
__global__ __launch_bounds__(192) void pool_ln_kernel(
    const float* __restrict__ x,
    const float* __restrict__ wq9, const float* __restrict__ wk9, const float* __restrict__ wv9,
    const float* __restrict__ gq, const float* __restrict__ bq,
    const float* __restrict__ gk, const float* __restrict__ bk,
    const float* __restrict__ gv, const float* __restrict__ bv,
    short* __restrict__ Pq, short* __restrict__ Pk, short* __restrict__ Pv)
{
  __shared__ __align__(16) float wt_s[3][9][64];   // [conv][tap][c]
  int tid = threadIdx.x;
  int blk = blockIdx.x;
  int b = blk / 197;
  int n0 = (blk - b * 197) * 4;

  for (int idx = tid; idx < 3 * 576; idx += 192) {
    int conv = idx / 576, rem = idx - conv * 576;
    int c = rem / 9, tap = rem - c * 9;
    const float* wsrc = (conv == 0) ? wq9 : (conv == 1) ? wk9 : wv9;
    wt_s[conv][tap][c] = wsrc[c * 9 + tap];
  }
  __syncthreads();

  int ch0 = tid * 4;
  int c4 = ch0 & 63;
  f32x4 g_q = *(const f32x4*)&gq[c4], b_q = *(const f32x4*)&bq[c4];
  f32x4 g_k = *(const f32x4*)&gk[c4], b_k = *(const f32x4*)&bk[c4];
  f32x4 g_v = *(const f32x4*)&gv[c4], b_v = *(const f32x4*)&bv[c4];

  for (int tt = 0; tt < 4; ++tt) {
    int n = n0 + tt;
    if (n >= NTOK) break;
    f32x4 aq = (f32x4){0.f, 0.f, 0.f, 0.f}, ak = aq, av = aq;
    if (n == 0) {
      f32x4 x4 = *(const f32x4*)&x[((size_t)b * NIN) * DMODEL + ch0];
      aq = ak = av = x4;
    } else {
      int s = n - 1;
      int i = s / PHDIM, j = s - i * PHDIM;
#pragma unroll
      for (int di = 0; di < 3; ++di) {
        int ii = 2 * i - 1 + di;
        if (ii < 0 || ii >= HWDIM) continue;
#pragma unroll
        for (int dj = 0; dj < 3; ++dj) {
          int jj = 2 * j - 1 + dj;
          if (jj < 0 || jj >= HWDIM) continue;
          f32x4 x4 = *(const f32x4*)&x[((size_t)b * NIN + 1 + ii * HWDIM + jj) * DMODEL + ch0];
          int tap = di * 3 + dj;
          f32x4 w0 = *(const f32x4*)&wt_s[0][tap][c4];
          f32x4 w1 = *(const f32x4*)&wt_s[1][tap][c4];
          f32x4 w2 = *(const f32x4*)&wt_s[2][tap][c4];
          aq += w0 * x4; ak += w1 * x4; av += w2 * x4;
        }
      }
    }
    size_t obase = ((size_t)b * NTOK + n) * DMODEL + ch0;
    {
      float sm = aq[0] + aq[1] + aq[2] + aq[3];
#pragma unroll
      for (int m = 1; m < 16; m <<= 1) sm += __shfl_xor(sm, m);
      float mn = sm * (1.f / 64.f);
      f32x4 d = aq - mn;
      float vs = d[0]*d[0] + d[1]*d[1] + d[2]*d[2] + d[3]*d[3];
#pragma unroll
      for (int m = 1; m < 16; m <<= 1) vs += __shfl_xor(vs, m);
      float rs = rsqrtf(vs * (1.f / 64.f) + 1e-5f);
      s16x4 o;
#pragma unroll
      for (int e = 0; e < 4; ++e) o[e] = f2bf(d[e] * rs * g_q[e] + b_q[e]);
      *(s16x4*)&Pq[obase] = o;
    }
    {
      float sm = ak[0] + ak[1] + ak[2] + ak[3];
#pragma unroll
      for (int m = 1; m < 16; m <<= 1) sm += __shfl_xor(sm, m);
      float mn = sm * (1.f / 64.f);
      f32x4 d = ak - mn;
      float vs = d[0]*d[0] + d[1]*d[1] + d[2]*d[2] + d[3]*d[3];
#pragma unroll
      for (int m = 1; m < 16; m <<= 1) vs += __shfl_xor(vs, m);
      float rs = rsqrtf(vs * (1.f / 64.f) + 1e-5f);
      s16x4 o;
#pragma unroll
      for (int e = 0; e < 4; ++e) o[e] = f2bf(d[e] * rs * g_k[e] + b_k[e]);
      *(s16x4*)&Pk[obase] = o;
    }
    {
      float sm = av[0] + av[1] + av[2] + av[3];
#pragma unroll
      for (int m = 1; m < 16; m <<= 1) sm += __shfl_xor(sm, m);
      float mn = sm * (1.f / 64.f);
      f32x4 d = av - mn;
      float vs = d[0]*d[0] + d[1]*d[1] + d[2]*d[2] + d[3]*d[3];
#pragma unroll
      for (int m = 1; m < 16; m <<= 1) vs += __shfl_xor(vs, m);
      float rs = rsqrtf(vs * (1.f / 64.f) + 1e-5f);
      s16x4 o;
#pragma unroll
      for (int e = 0; e < 4; ++e) o[e] = f2bf(d[e] * rs * g_v[e] + b_v[e]);
      *(s16x4*)&Pv[obase] = o;
    }
  }
}

// ------------------------------------------------- weight transpose fp32->bf16
__global__ __launch_bounds__(256) void trans_kernel(
    const float* __restrict__ s0, const float* __restrict__ s1,
    const float* __restrict__ s2, const float* __restrict__ s3,
    short* __restrict__ d0, short* __restrict__ d1,
    short* __restrict__ d2, short* __restrict__ d3)
{
  __shared__ float tile[32][33];
  int z = blockIdx.z;
  const float* s = (z == 0) ? s0 : (z == 1) ? s1 : (z == 2) ? s2 : s3;
  short* d = (z == 0) ? d0 : (z == 1) ? d1 : (z == 2) ? d2 : d3;
  int k0 = blockIdx.x * 32, n0 = blockIdx.y * 32;
  int tx = threadIdx.x, ty = threadIdx.y;   // 32 x 8
#pragma unroll
  for (int jj = 0; jj < 4; ++jj)
    tile[ty + jj * 8][tx] = s[(size_t)(k0 + ty + jj * 8) * DMODEL + n0 + tx];
  __syncthreads();
#pragma unroll
  for (int jj = 0; jj < 4; ++jj)
    d[(size_t)(n0 + ty + jj * 8) * DMODEL + k0 + tx] = f2bf(tile[tx][ty + jj * 8]);
}

// ------------------------------------------------------------- GEMM core
// C[128,128] tile of A[M,768] @ Bt[N,768]^T + bias
// mode0: fp32 row-major, bias[col]; mode1: bf16 (B,12,785,64), bias[col];
// mode2: bf16 transposed out[(b*768+row)*785+n], bias[row]
static __device__ __forceinline__ void gemm_core(
    short* As, short* Bs,
    const short* __restrict__ A, const short* __restrict__ Bt,
    const float* __restrict__ bias, void* __restrict__ outp,
    int rowbase, int colbase, int M, int Nn, int mode)
{
  const int K = DMODEL;
  int tid = threadIdx.x;
  int wid = tid >> 6, lane = tid & 63;
  int lg = lane >> 4, lq = lane & 15;
  int wm = wid >> 1, wn = wid & 1;

  f32x4 acc[4][4];
#pragma unroll
  for (int i = 0; i < 4; ++i)
#pragma unroll
    for (int j = 0; j < 4; ++j) acc[i][j] = (f32x4){0.f, 0.f, 0.f, 0.f};

  int srow = tid >> 2;
  int scol = (tid & 3) * 8;
  int ar0 = min(rowbase + srow, M - 1);
  int ar1 = min(rowbase + 64 + srow, M - 1);
  int br0 = min(colbase + srow, Nn - 1);
  int br1 = min(colbase + 64 + srow, Nn - 1);
  const short* Ag0 = A + (size_t)ar0 * K + scol;
  const short* Ag1 = A + (size_t)ar1 * K + scol;
  const short* Bg0 = Bt + (size_t)br0 * K + scol;
  const short* Bg1 = Bt + (size_t)br1 * K + scol;
  short* AsW0 = As + wid * 512;
  short* AsW1 = As + 2048 + wid * 512;
  short* BsW0 = Bs + wid * 512;
  short* BsW1 = Bs + 2048 + wid * 512;

  for (int kt = 0; kt < K; kt += 32) {
    __syncthreads();
    gl_lds16(Ag0 + kt, AsW0);
    gl_lds16(Ag1 + kt, AsW1);
    gl_lds16(Bg0 + kt, BsW0);
    gl_lds16(Bg1 + kt, BsW1);
    __syncthreads();
    bf16x8 aFrag[4], bFrag[4];
#pragma unroll
    for (int mi = 0; mi < 4; ++mi)
      aFrag[mi] = *(const bf16x8*)&As[(wm * 64 + mi * 16 + lq) * 32 + lg * 8];
#pragma unroll
    for (int ni = 0; ni < 4; ++ni)
      bFrag[ni] = *(const bf16x8*)&Bs[(wn * 64 + ni * 16 + lq) * 32 + lg * 8];
    __builtin_amdgcn_s_setprio(1);
#pragma unroll
    for (int mi = 0; mi < 4; ++mi)
#pragma unroll
      for (int ni = 0; ni < 4; ++ni)
        acc[mi][ni] = __builtin_amdgcn_mfma_f32_16x16x32_bf16(aFrag[mi], bFrag[ni], acc[mi][ni], 0, 0, 0);
    __builtin_amdgcn_s_setprio(0);
  }

#pragma unroll
  for (int mi = 0; mi < 4; ++mi) {
    int rowq = rowbase + wm * 64 + mi * 16 + lg * 4;
#pragma unroll
    for (int r = 0; r < 4; ++r) {
      int row = rowq + r;
      if (row < M) {
        if (mode == 2) {
          float bb = bias[row];
#pragma unroll
          for (int ni = 0; ni < 4; ++ni) {
            int col = colbase + wn * 64 + ni * 16 + lq;
            if (col < Nn) {
              int b = col / NTOK, n = col - b * NTOK;
              float v = acc[mi][ni][r] + bb;
              ((short*)outp)[((size_t)b * DMODEL + row) * NTOK + n] = f2bf(v);
            }
          }
        } else {
          int bb = row / NTOK;
          int nn = row - bb * NTOK;
#pragma unroll
          for (int ni = 0; ni < 4; ++ni) {
            int col = colbase + wn * 64 + ni * 16 + lq;
            float v = acc[mi][ni][r] + bias[col];
            if (mode == 0) {
              ((float*)outp)[(size_t)row * DMODEL + col] = v;
            } else {
              ((short*)outp)[(((size_t)(bb * NUM_HEADS + (col >> 6)) * NTOK + nn) << 6) + (col & 63)] = f2bf(v);
            }
          }
        }
      }
    }
  }
}

// fused Q-proj / K-proj / V^T-proj: 1782 blocks, XCD-chunked, col-fastest.
__global__ __launch_bounds__(256) void gemm_qkv_kernel(
    const short* __restrict__ Pq, const short* __restrict__ WqT,
    const float* __restrict__ bq, short* __restrict__ qhd,
    const short* __restrict__ Pk, const short* __restrict__ WkT,
    const float* __restrict__ bk, short* __restrict__ khd,
    const short* __restrict__ WvT, const short* __restrict__ Pv,
    const float* __restrict__ bv, short* __restrict__ vtg)
{
  __shared__ short As[128 * 32];
  __shared__ short Bs[128 * 32];
  const int NWG = 1782;
  int lid = xcd_chunk(blockIdx.x, NWG);
  if (lid < 1188) {
    int which = lid / 594;
    int sub = lid - which * 594;
    int rowbase = (sub / 6) * 128;     // col fastest: 6 consecutive share A panel
    int colbase = (sub % 6) * 128;
    gemm_core(As, Bs,
              which ? Pk : Pq, which ? WkT : WqT,
              which ? bk : bq, which ? (void*)khd : (void*)qhd,
              rowbase, colbase, BATCH * NTOK, DMODEL, 1);
  } else {
    int sub = lid - 1188;
    int rowbase = (sub % 6) * 128;     // row (WvT) fastest: share Pv col panel
    int colbase = (sub / 6) * 128;
    gemm_core(As, Bs, WvT, Pv, bv, (void*)vtg,
              rowbase, colbase, DMODEL, BATCH * NTOK, 2);
  }
}

// final projection: 594 blocks, XCD-chunked, col-fastest
__global__ __launch_bounds__(256) void gemm_proj_kernel(
    const short* __restrict__ Afin, const short* __restrict__ WpT,
    const float* __restrict__ bp, float* __restrict__ outp)
{
  __shared__ short As[128 * 32];
  __shared__ short Bs[128 * 32];
  const int NWG = 594;
  int lid = xcd_chunk(blockIdx.x, NWG);
  int rowbase = (lid / 6) * 128;
  int colbase = (lid % 6) * 128;
  gemm_core(As, Bs, Afin, WpT, bp, (void*)outp,
            rowbase, colbase, BATCH * NTOK, DMODEL, 0);
}

// -------------------------------------------------------- rel-pos bias tables
// transposed bf16 output, pre-scaled by log2e: RelHt[bh][kk][qrow]
__global__ __launch_bounds__(256) void relbias_kernel(
    const short* __restrict__ qh, const float* __restrict__ rph,
    const float* __restrict__ rpw, short* __restrict__ RelHt, short* __restrict__ RelWt)
{
  int line = blockIdx.x;   // i (mode0) or j (mode1)
  int bh = blockIdx.y;
  int mode = blockIdx.z;
  __shared__ __align__(16) float qt_s[28 * 68];
  __shared__ __align__(16) float rt_s[28 * 68];
  int tid = threadIdx.x;
  const float* rp = (mode == 0) ? rph : rpw;
  for (int idx = tid; idx < 28 * 64; idx += 256) {
    int rr = idx >> 6, c = idx & 63;
    int qi = (mode == 0) ? (1 + line * PHDIM + rr) : (1 + rr * PHDIM + line);
    qt_s[rr * 68 + c] = bf2f(qh[((size_t)bh * NTOK + qi) * HEAD_DIM + c]);
    rt_s[rr * 68 + c] = rp[(line - rr + 27) * HEAD_DIM + c];
  }
  __syncthreads();
  short* dst = (mode == 0) ? RelHt : RelWt;
  for (int o = tid; o < 784; o += 256) {
    int kk = o / PHDIM, rr = o - kk * PHDIM;
    const f32x4* qa = (const f32x4*)&qt_s[rr * 68];
    const f32x4* ra = (const f32x4*)&rt_s[kk * 68];
    f32x4 a4 = (f32x4){0.f, 0.f, 0.f, 0.f};
#pragma unroll
    for (int i = 0; i < 16; ++i) a4 += qa[i] * ra[i];
    float s = (a4[0] + a4[1] + a4[2] + a4[3]) * LOG2E;
    int qrow = (mode == 0) ? (line * PHDIM + rr) : (rr * PHDIM + line);
    dst[((size_t)bh * PHDIM + kk) * 784 + qrow] = f2bf(s);
  }
}

// ------------------------------------------------------------ flash attention
__global__ __launch_bounds__(256) void flash5_kernel(
    const short* __restrict__ qh, const short* __restrict__ kh, const short* __restrict__ vtg,
    const short* __restrict__ RelHt, const short* __restrict__ RelWt,
    short* __restrict__ Afin)
{
  int id = blockIdx.x;
  int slot = id >> 3;
  int bh = (id & 7) * 24 + slot / 13;   // all 13 q-tiles of a bh on one XCD
  int qt = slot - (slot / 13) * 13;
  int qbase = qt * 64;
  int tid = threadIdx.x, wid = tid >> 6, lane = tid & 63;
  int lg = lane >> 4, lq = lane & 15;

  __shared__ __align__(16) short ks[64 * 64];      // sigma-permuted K rows, chunk-swizzled
  __shared__ __align__(16) short vt[64 * 64];      // V^T[d][key], key-chunks swizzled by d&7
  __shared__ __align__(16) float relh_t[28][64];   // [ki][q_local], log2e-scaled
  __shared__ __align__(16) float relw_t[28][64];
  __shared__ __align__(16) float axl[4][16];

  for (int idx = tid; idx < 28 * 64; idx += 256) {
    int kk = idx >> 6, ql = idx & 63;
    int qi = qbase + ql;
    float rh = 0.f, rw = 0.f;
    if (qi >= 1 && qi < NTOK) {
      rh = bf2f(RelHt[((size_t)bh * PHDIM + kk) * 784 + qi - 1]);
      rw = bf2f(RelWt[((size_t)bh * PHDIM + kk) * 784 + qi - 1]);
    }
    relh_t[kk][ql] = rh; relw_t[kk][ql] = rw;
  }

  int qi0 = qbase + wid * 16 + lq;
  int qiq = min(qi0, NTOK - 1);
  const short* qrow = qh + ((size_t)bh * NTOK + qiq) * HEAD_DIM;
  bf16x8 bq0 = *(const bf16x8*)(qrow + lg * 8);
  bf16x8 bq1 = *(const bf16x8*)(qrow + 32 + lg * 8);

  float m_l = -3e30f, l_l = 0.f;
  f32x4 acc[4];
#pragma unroll
  for (int ch = 0; ch < 4; ++ch) acc[ch] = (f32x4){0.f, 0.f, 0.f, 0.f};

  const float scale2 = 0.125f * LOG2E;
  int q_local = wid * 16 + lq;
  const short* kbase = kh + (size_t)bh * NTOK * HEAD_DIM;
  const short* vbase = vtg + (size_t)bh * (size_t)HEAD_DIM * NTOK;

  int c0 = tid, c1 = 256 + tid;
  int rr0 = c0 >> 3, j0 = c0 & 7;
  int rr1 = c1 >> 3, j1 = c1 & 7;
  int koff0 = ((rr0 & 15) >> 2) * 16 + (rr0 >> 4) * 4 + (rr0 & 3);
  int koff1 = ((rr1 & 15) >> 2) * 16 + (rr1 >> 4) * 4 + (rr1 & 3);
  int ksw0 = (j0 ^ (rr0 & 7)) << 3;
  int ksw1 = (j1 ^ (rr1 & 7)) << 3;
  int vsw0 = (j0 ^ (rr0 & 7)) << 3;
  int vsw1 = (j1 ^ (rr1 & 7)) << 3;
  const short* vsrc0 = vbase + (size_t)rr0 * NTOK + vsw0;
  const short* vsrc1 = vbase + (size_t)rr1 * NTOK + vsw1;

  auto step_body = [&](int kvb, bool first, bool last) __attribute__((always_inline)) {
    __syncthreads();
    gl_lds16(kbase + (size_t)min(kvb + koff0, NTOK - 1) * HEAD_DIM + ksw0, ks + wid * 512);
    gl_lds16(kbase + (size_t)min(kvb + koff1, NTOK - 1) * HEAD_DIM + ksw1, ks + 2048 + wid * 512);
    gl_lds16(vsrc0 + kvb, vt + wid * 512);
    gl_lds16(vsrc1 + kvb, vt + 2048 + wid * 512);
    __syncthreads();

    int base = kvb + 16 * lg;
    int km1 = base - 1;
    int t = max(km1, 0);
    int ki = t / PHDIM;
    int kj = t - ki * PHDIM;
    if (km1 < 0) kj = -1;

    float p[16];
#pragma unroll
    for (int kt = 0; kt < 4; ++kt) {
      int kl = kt * 16 + lq;
      const char* kp = (const char*)ks + kl * 128;
      int swz = kl & 7;
      bf16x8 aK0 = *(const bf16x8*)(kp + ((lg ^ swz) << 4));
      bf16x8 aK1 = *(const bf16x8*)(kp + (((lg + 4) ^ swz) << 4));
      f32x4 s = (f32x4){0.f, 0.f, 0.f, 0.f};
      __builtin_amdgcn_s_setprio(1);
      s = __builtin_amdgcn_mfma_f32_16x16x32_bf16(aK0, bq0, s, 0, 0, 0);
      s = __builtin_amdgcn_mfma_f32_16x16x32_bf16(aK1, bq1, s, 0, 0, 0);
      __builtin_amdgcn_s_setprio(0);
#pragma unroll
      for (int r = 0; r < 4; ++r) {
        int i = kt * 4 + r;
        float v = s[r] * scale2;
        if (first) {
          int key = base + i;
          if (key >= 1) v += relh_t[ki][q_local] + relw_t[kj][q_local];
        } else if (last) {
          int key = base + i;
          v += relh_t[ki][q_local] + relw_t[kj][q_local];
          if (key >= NTOK) v = -3e30f;
        } else {
          v += relh_t[ki][q_local] + relw_t[kj][q_local];
        }
        p[i] = v;
        ++kj;
        if (kj == PHDIM) { kj = 0; ++ki; }
      }
    }

    float pm = p[0];
#pragma unroll
    for (int i = 1; i < 16; ++i) pm = fmaxf(pm, p[i]);
    pm = fmaxf(pm, __shfl_xor(pm, 16));
    pm = fmaxf(pm, __shfl_xor(pm, 32));
    if (!__all(pm - m_l <= 11.5f)) {
      float mnew = fmaxf(m_l, pm);
      float alpha = fexp2(m_l - mnew);
      m_l = mnew;
      l_l *= alpha;
      if (lg == 0) axl[wid][lq] = alpha;
      f32x4 av = *(const f32x4*)&axl[wid][lg * 4];
#pragma unroll
      for (int ch = 0; ch < 4; ++ch)
#pragma unroll
        for (int r = 0; r < 4; ++r) acc[ch][r] *= av[r];
    }
    float ps = 0.f;
#pragma unroll
    for (int i = 0; i < 16; ++i) { p[i] = fexp2(p[i] - m_l); ps += p[i]; }
    ps += __shfl_xor(ps, 16);
    ps += __shfl_xor(ps, 32);
    l_l += ps;

    bf16x8 pa0, pa1;
#pragma unroll
    for (int j = 0; j < 4; ++j) {
      unsigned u0, u1, v0, v1;
      __builtin_memcpy(&u0, &p[2 * j], 4);
      __builtin_memcpy(&u1, &p[2 * j + 1], 4);
      __builtin_memcpy(&v0, &p[8 + 2 * j], 4);
      __builtin_memcpy(&v1, &p[8 + 2 * j + 1], 4);
      ((unsigned*)&pa0)[j] = (u0 >> 16) | (u1 & 0xFFFF0000u);
      ((unsigned*)&pa1)[j] = (v0 >> 16) | (v1 & 0xFFFF0000u);
    }
    __builtin_amdgcn_s_setprio(1);
#pragma unroll
    for (int ch = 0; ch < 4; ++ch) {
      int d = ch * 16 + lq;
      const char* vrow = (const char*)vt + d * 128;
      int swz = lq & 7;
      bf16x8 bv0 = *(const bf16x8*)(vrow + (((2 * lg + 0) ^ swz) << 4));
      bf16x8 bv1 = *(const bf16x8*)(vrow + (((2 * lg + 1) ^ swz) << 4));
      acc[ch] = __builtin_amdgcn_mfma_f32_16x16x32_bf16(pa0, bv0, acc[ch], 0, 0, 0);
      acc[ch] = __builtin_amdgcn_mfma_f32_16x16x32_bf16(pa1, bv1, acc[ch], 0, 0, 0);
    }
    __builtin_amdgcn_s_setprio(0);
  };

  step_body(0, true, false);
  for (int step = 1; step < 12; ++step) step_body(step * 64, false, false);
  step_body(12 * 64, false, true);

  if (lg == 0) axl[wid][lq] = l_l;
  f32x4 lv = *(const f32x4*)&axl[wid][lg * 4];
  int b = bh / NUM_HEADS, h = bh - b * NUM_HEADS;
#pragma unroll
  for (int r = 0; r < 4; ++r) {
    int qi = qbase + wid * 16 + lg * 4 + r;
    if (qi < NTOK) {
      float inv = 1.f / lv[r];
#pragma unroll
      for (int ch = 0; ch < 4; ++ch) {
        int d = ch * 16 + lq;
        float o = acc[ch][r] * inv + bf2f(qh[((size_t)bh * NTOK + qi) * HEAD_DIM + d]);
        Afin[((size_t)b * NTOK + qi) * DMODEL + h * HEAD_DIM + d] = f2bf(o);
      }
    }
  }
}

// ------------------------------------------------------------------- launcher
extern "C" void kernel_launch(void* const* d_in, const int* in_sizes, int n_in,
                              void* d_out, int out_size, void* d_ws, size_t ws_size,
                              hipStream_t stream)
{
  (void)in_sizes; (void)n_in; (void)out_size; (void)ws_size;
  const float* x   = (const float*)d_in[0];
  const float* pqw = (const float*)d_in[1];
  const float* pkw = (const float*)d_in[2];
  const float* pvw = (const float*)d_in[3];
  const float* gq  = (const float*)d_in[4];
  const float* bq_ = (const float*)d_in[5];
  const float* gk  = (const float*)d_in[6];
  const float* bk_ = (const float*)d_in[7];
  const float* gv  = (const float*)d_in[8];
  const float* bv_ = (const float*)d_in[9];
  const float* wq  = (const float*)d_in[10];
  const float* bqp = (const float*)d_in[11];
  const float* wk  = (const float*)d_in[12];
  const float* bkp = (const float*)d_in[13];
  const float* wv  = (const float*)d_in[14];
  const float* bvp = (const float*)d_in[15];
  const float* wp  = (const float*)d_in[16];
  const float* bpp = (const float*)d_in[17];
  const float* rph = (const float*)d_in[18];
  const float* rpw = (const float*)d_in[19];

  char* ws = (char*)d_ws;
  size_t off = 0;
  auto alloc = [&](size_t bytes) -> void* {
    void* p = ws + off; off += (bytes + 255) & ~(size_t)255; return p;
  };
  const size_t MROWS = (size_t)BATCH * NTOK;   // 12560
  short* Pq  = (short*)alloc(MROWS * DMODEL * 2);
  short* Pk  = (short*)alloc(MROWS * DMODEL * 2);
  short* Pv  = (short*)alloc(MROWS * DMODEL * 2);
  short* WqT = (short*)alloc((size_t)DMODEL * DMODEL * 2);
  short* WkT = (short*)alloc((size_t)DMODEL * DMODEL * 2);
  short* WvT = (short*)alloc((size_t)DMODEL * DMODEL * 2);
  short* WpT = (short*)alloc((size_t)DMODEL * DMODEL * 2);
  short* qhd = (short*)alloc(MROWS * DMODEL * 2 + 4096);
  short* khd = (short*)alloc(MROWS * DMODEL * 2 + 4096);
  short* vtg = (short*)alloc(MROWS * DMODEL * 2 + 8192);  // transposed V
  short* RelHt = (short*)alloc((size_t)BHCNT * 784 * 28 * 2);
  short* RelWt = (short*)alloc((size_t)BHCNT * 784 * 28 * 2);
  short* Afin = (short*)alloc(MROWS * DMODEL * 2);

  pool_ln_kernel<<<dim3(16 * 197), 192, 0, stream>>>(
      x, pqw, pkw, pvw, gq, bq_, gk, bk_, gv, bv_, Pq, Pk, Pv);
  trans_kernel<<<dim3(24, 24, 4), dim3(32, 8), 0, stream>>>(
      wq, wk, wv, wp, WqT, WkT, WvT, WpT);
  gemm_qkv_kernel<<<dim3(1782), 256, 0, stream>>>(
      Pq, WqT, bqp, qhd, Pk, WkT, bkp, khd, WvT, Pv, bvp, vtg);
  relbias_kernel<<<dim3(28, BHCNT, 2), 256, 0, stream>>>(qhd, rph, rpw, RelHt, RelWt);
  flash5_kernel<<<dim3(2496), 256, 0, stream>>>(qhd, khd, vtg, RelHt, RelWt, Afin);
  gemm_proj_kernel<<<dim3(594), 256, 0, stream>>>(Afin, WpT, bpp, (float*)d_out);
}

// Round 8
// 369.980 us; speedup vs baseline: 1.7062x; 1.0748x over previous
//
#include <hip/hip_runtime.h>
#include <stdint.h>

#define NUM_HEADS 12
#define HEAD_DIM  64
#define HWDIM     56
#define PHDIM     28
#define NTOK      785     // 28*28+1
#define NIN       3137    // 56*56+1
#define BATCH     16
#define DMODEL    768
#define BHCNT     192     // BATCH*NUM_HEADS
#define LOG2E     1.44269504f

typedef __attribute__((ext_vector_type(8))) short bf16x8;
typedef __attribute__((ext_vector_type(4))) short s16x4;
typedef __attribute__((ext_vector_type(4))) float f32x4;

static __device__ __forceinline__ float bf2f(short s) {
  unsigned u = ((unsigned)(unsigned short)s) << 16;
  float f; __builtin_memcpy(&f, &u, 4); return f;
}
static __device__ __forceinline__ short f2bf(float f) {
  unsigned u; __builtin_memcpy(&u, &f, 4);
  unsigned r = u + 0x7FFFu + ((u >> 16) & 1u);
  return (short)(r >> 16);
}
static __device__ __forceinline__ float fexp2(float x) {
#if defined(__has_builtin)
#if __has_builtin(__builtin_amdgcn_exp2f)
  return __builtin_amdgcn_exp2f(x);
#else
  return exp2f(x);
#endif
#else
  return exp2f(x);
#endif
}

// bijective XCD chunking (m204)
static __device__ __forceinline__ int xcd_chunk(int orig, int nwg) {
  int xcd = orig & 7;
  int within = orig >> 3;
  int q = nwg >> 3, r = nwg & 7;
  int base = (xcd < r) ? xcd * (q + 1) : r * (q + 1) + (xcd - r) * q;
  return base + within;
}

#if defined(__has_builtin)
#if __has_builtin(__builtin_amdgcn_global_load_lds)
#define HAVE_GLLDS 1
#endif
#endif

static __device__ __forceinline__ void gl_lds16(const short* g, short* l) {
#ifdef HAVE_GLLDS
  __builtin_amdgcn_global_load_lds(
      (const __attribute__((address_space(1))) void*)g,
      (__attribute__((address_space(3))) void*)l, 16, 0, 0);
#else
  int lane = threadIdx.x & 63;
  *(bf16x8*)(l + lane * 8) = *(const bf16x8*)g;
#endif
}

// ---------------------------------------------------------------- pool + LN
__global__ __launch_bounds__(192) void pool_ln_kernel(
    const float* __restrict__ x,
    const float* __restrict__ wq9, const float* __restrict__ wk9, const float* __restrict__ wv9,
    const float* __restrict__ gq, const float* __restrict__ bq,
    const float* __restrict__ gk, const float* __restrict__ bk,
    const float* __restrict__ gv, const float* __restrict__ bv,
    short* __restrict__ Pq, short* __restrict__ Pk, short* __restrict__ Pv)
{
  __shared__ __align__(16) float wt_s[3][9][64];   // [conv][tap][c]
  int tid = threadIdx.x;
  int blk = blockIdx.x;
  int b = blk / 197;
  int n0 = (blk - b * 197) * 4;

  for (int idx = tid; idx < 3 * 576; idx += 192) {
    int conv = idx / 576, rem = idx - conv * 576;
    int c = rem / 9, tap = rem - c * 9;
    const float* wsrc = (conv == 0) ? wq9 : (conv == 1) ? wk9 : wv9;
    wt_s[conv][tap][c] = wsrc[c * 9 + tap];
  }
  __syncthreads();

  int ch0 = tid * 4;
  int c4 = ch0 & 63;
  f32x4 g_q = *(const f32x4*)&gq[c4], b_q = *(const f32x4*)&bq[c4];
  f32x4 g_k = *(const f32x4*)&gk[c4], b_k = *(const f32x4*)&bk[c4];
  f32x4 g_v = *(const f32x4*)&gv[c4], b_v = *(const f32x4*)&bv[c4];

  for (int tt = 0; tt < 4; ++tt) {
    int n = n0 + tt;
    if (n >= NTOK) break;
    f32x4 aq = (f32x4){0.f, 0.f, 0.f, 0.f}, ak = aq, av = aq;
    if (n == 0) {
      f32x4 x4 = *(const f32x4*)&x[((size_t)b * NIN) * DMODEL + ch0];
      aq = ak = av = x4;
    } else {
      int s = n - 1;
      int i = s / PHDIM, j = s - i * PHDIM;
#pragma unroll
      for (int di = 0; di < 3; ++di) {
        int ii = 2 * i - 1 + di;
        if (ii < 0 || ii >= HWDIM) continue;
#pragma unroll
        for (int dj = 0; dj < 3; ++dj) {
          int jj = 2 * j - 1 + dj;
          if (jj < 0 || jj >= HWDIM) continue;
          f32x4 x4 = *(const f32x4*)&x[((size_t)b * NIN + 1 + ii * HWDIM + jj) * DMODEL + ch0];
          int tap = di * 3 + dj;
          f32x4 w0 = *(const f32x4*)&wt_s[0][tap][c4];
          f32x4 w1 = *(const f32x4*)&wt_s[1][tap][c4];
          f32x4 w2 = *(const f32x4*)&wt_s[2][tap][c4];
          aq += w0 * x4; ak += w1 * x4; av += w2 * x4;
        }
      }
    }
    size_t obase = ((size_t)b * NTOK + n) * DMODEL + ch0;
    {
      float sm = aq[0] + aq[1] + aq[2] + aq[3];
#pragma unroll
      for (int m = 1; m < 16; m <<= 1) sm += __shfl_xor(sm, m);
      float mn = sm * (1.f / 64.f);
      f32x4 d = aq - mn;
      float vs = d[0]*d[0] + d[1]*d[1] + d[2]*d[2] + d[3]*d[3];
#pragma unroll
      for (int m = 1; m < 16; m <<= 1) vs += __shfl_xor(vs, m);
      float rs = rsqrtf(vs * (1.f / 64.f) + 1e-5f);
      s16x4 o;
#pragma unroll
      for (int e = 0; e < 4; ++e) o[e] = f2bf(d[e] * rs * g_q[e] + b_q[e]);
      *(s16x4*)&Pq[obase] = o;
    }
    {
      float sm = ak[0] + ak[1] + ak[2] + ak[3];
#pragma unroll
      for (int m = 1; m < 16; m <<= 1) sm += __shfl_xor(sm, m);
      float mn = sm * (1.f / 64.f);
      f32x4 d = ak - mn;
      float vs = d[0]*d[0] + d[1]*d[1] + d[2]*d[2] + d[3]*d[3];
#pragma unroll
      for (int m = 1; m < 16; m <<= 1) vs += __shfl_xor(vs, m);
      float rs = rsqrtf(vs * (1.f / 64.f) + 1e-5f);
      s16x4 o;
#pragma unroll
      for (int e = 0; e < 4; ++e) o[e] = f2bf(d[e] * rs * g_k[e] + b_k[e]);
      *(s16x4*)&Pk[obase] = o;
    }
    {
      float sm = av[0] + av[1] + av[2] + av[3];
#pragma unroll
      for (int m = 1; m < 16; m <<= 1) sm += __shfl_xor(sm, m);
      float mn = sm * (1.f / 64.f);
      f32x4 d = av - mn;
      float vs = d[0]*d[0] + d[1]*d[1] + d[2]*d[2] + d[3]*d[3];
#pragma unroll
      for (int m = 1; m < 16; m <<= 1) vs += __shfl_xor(vs, m);
      float rs = rsqrtf(vs * (1.f / 64.f) + 1e-5f);
      s16x4 o;
#pragma unroll
      for (int e = 0; e < 4; ++e) o[e] = f2bf(d[e] * rs * g_v[e] + b_v[e]);
      *(s16x4*)&Pv[obase] = o;
    }
  }
}

// ------------------------------------------------- weight transpose fp32->bf16
__global__ __launch_bounds__(256) void trans_kernel(
    const float* __restrict__ s0, const float* __restrict__ s1,
    const float* __restrict__ s2, const float* __restrict__ s3,
    short* __restrict__ d0, short* __restrict__ d1,
    short* __restrict__ d2, short* __restrict__ d3)
{
  __shared__ float tile[32][33];
  int z = blockIdx.z;
  const float* s = (z == 0) ? s0 : (z == 1) ? s1 : (z == 2) ? s2 : s3;
  short* d = (z == 0) ? d0 : (z == 1) ? d1 : (z == 2) ? d2 : d3;
  int k0 = blockIdx.x * 32, n0 = blockIdx.y * 32;
  int tx = threadIdx.x, ty = threadIdx.y;   // 32 x 8
#pragma unroll
  for (int jj = 0; jj < 4; ++jj)
    tile[ty + jj * 8][tx] = s[(size_t)(k0 + ty + jj * 8) * DMODEL + n0 + tx];
  __syncthreads();
#pragma unroll
  for (int jj = 0; jj < 4; ++jj)
    d[(size_t)(n0 + ty + jj * 8) * DMODEL + k0 + tx] = f2bf(tile[tx][ty + jj * 8]);
}

// ------------------------------------------------------------- GEMM core
// 2-phase double-buffered (T3 minimum): STAGE(next) -> compute(cur) -> 1 barrier.
// As/Bs are 2x4096-short double buffers.
static __device__ __forceinline__ void gemm_core(
    short* As, short* Bs,
    const short* __restrict__ A, const short* __restrict__ Bt,
    const float* __restrict__ bias, void* __restrict__ outp,
    int rowbase, int colbase, int M, int Nn, int mode)
{
  const int K = DMODEL;
  int tid = threadIdx.x;
  int wid = tid >> 6, lane = tid & 63;
  int lg = lane >> 4, lq = lane & 15;
  int wm = wid >> 1, wn = wid & 1;

  f32x4 acc[4][4];
#pragma unroll
  for (int i = 0; i < 4; ++i)
#pragma unroll
    for (int j = 0; j < 4; ++j) acc[i][j] = (f32x4){0.f, 0.f, 0.f, 0.f};

  int srow = tid >> 2;
  int scol = (tid & 3) * 8;
  int ar0 = min(rowbase + srow, M - 1);
  int ar1 = min(rowbase + 64 + srow, M - 1);
  int br0 = min(colbase + srow, Nn - 1);
  int br1 = min(colbase + 64 + srow, Nn - 1);
  const short* Ag0 = A + (size_t)ar0 * K + scol;
  const short* Ag1 = A + (size_t)ar1 * K + scol;
  const short* Bg0 = Bt + (size_t)br0 * K + scol;
  const short* Bg1 = Bt + (size_t)br1 * K + scol;

  auto stage = [&](int kt, int buf) __attribute__((always_inline)) {
    short* Ab = As + buf * 4096;
    short* Bb = Bs + buf * 4096;
    gl_lds16(Ag0 + kt, Ab + wid * 512);
    gl_lds16(Ag1 + kt, Ab + 2048 + wid * 512);
    gl_lds16(Bg0 + kt, Bb + wid * 512);
    gl_lds16(Bg1 + kt, Bb + 2048 + wid * 512);
  };

  stage(0, 0);
  __syncthreads();          // vmcnt(0) drain + barrier: buf0 ready
  int cur = 0;
  for (int kt = 0; kt < K; kt += 32) {
    if (kt + 32 < K) stage(kt + 32, cur ^ 1);   // loads in flight during compute
    const short* Ac = As + cur * 4096;
    const short* Bc = Bs + cur * 4096;
    bf16x8 aFrag[4], bFrag[4];
#pragma unroll
    for (int mi = 0; mi < 4; ++mi)
      aFrag[mi] = *(const bf16x8*)&Ac[(wm * 64 + mi * 16 + lq) * 32 + lg * 8];
#pragma unroll
    for (int ni = 0; ni < 4; ++ni)
      bFrag[ni] = *(const bf16x8*)&Bc[(wn * 64 + ni * 16 + lq) * 32 + lg * 8];
    __builtin_amdgcn_s_setprio(1);
#pragma unroll
    for (int mi = 0; mi < 4; ++mi)
#pragma unroll
      for (int ni = 0; ni < 4; ++ni)
        acc[mi][ni] = __builtin_amdgcn_mfma_f32_16x16x32_bf16(aFrag[mi], bFrag[ni], acc[mi][ni], 0, 0, 0);
    __builtin_amdgcn_s_setprio(0);
    __syncthreads();        // single sync point: drains next-tile loads (hidden)
    cur ^= 1;
  }

#pragma unroll
  for (int mi = 0; mi < 4; ++mi) {
    int rowq = rowbase + wm * 64 + mi * 16 + lg * 4;
#pragma unroll
    for (int r = 0; r < 4; ++r) {
      int row = rowq + r;
      if (row < M) {
        if (mode == 2) {
          float bb = bias[row];
#pragma unroll
          for (int ni = 0; ni < 4; ++ni) {
            int col = colbase + wn * 64 + ni * 16 + lq;
            if (col < Nn) {
              int b = col / NTOK, n = col - b * NTOK;
              float v = acc[mi][ni][r] + bb;
              ((short*)outp)[((size_t)b * DMODEL + row) * NTOK + n] = f2bf(v);
            }
          }
        } else {
          int bb = row / NTOK;
          int nn = row - bb * NTOK;
#pragma unroll
          for (int ni = 0; ni < 4; ++ni) {
            int col = colbase + wn * 64 + ni * 16 + lq;
            float v = acc[mi][ni][r] + bias[col];
            if (mode == 0) {
              ((float*)outp)[(size_t)row * DMODEL + col] = v;
            } else {
              ((short*)outp)[(((size_t)(bb * NUM_HEADS + (col >> 6)) * NTOK + nn) << 6) + (col & 63)] = f2bf(v);
            }
          }
        }
      }
    }
  }
}

// fused Q-proj / K-proj / V^T-proj: 1782 blocks, XCD-chunked, col-fastest.
__global__ __launch_bounds__(256) void gemm_qkv_kernel(
    const short* __restrict__ Pq, const short* __restrict__ WqT,
    const float* __restrict__ bq, short* __restrict__ qhd,
    const short* __restrict__ Pk, const short* __restrict__ WkT,
    const float* __restrict__ bk, short* __restrict__ khd,
    const short* __restrict__ WvT, const short* __restrict__ Pv,
    const float* __restrict__ bv, short* __restrict__ vtg)
{
  __shared__ short As[2 * 4096];
  __shared__ short Bs[2 * 4096];
  const int NWG = 1782;
  int lid = xcd_chunk(blockIdx.x, NWG);
  if (lid < 1188) {
    int which = lid / 594;
    int sub = lid - which * 594;
    int rowbase = (sub / 6) * 128;
    int colbase = (sub % 6) * 128;
    gemm_core(As, Bs,
              which ? Pk : Pq, which ? WkT : WqT,
              which ? bk : bq, which ? (void*)khd : (void*)qhd,
              rowbase, colbase, BATCH * NTOK, DMODEL, 1);
  } else {
    int sub = lid - 1188;
    int rowbase = (sub % 6) * 128;
    int colbase = (sub / 6) * 128;
    gemm_core(As, Bs, WvT, Pv, bv, (void*)vtg,
              rowbase, colbase, DMODEL, BATCH * NTOK, 2);
  }
}

// final projection: 594 blocks, XCD-chunked, col-fastest
__global__ __launch_bounds__(256) void gemm_proj_kernel(
    const short* __restrict__ Afin, const short* __restrict__ WpT,
    const float* __restrict__ bp, float* __restrict__ outp)
{
  __shared__ short As[2 * 4096];
  __shared__ short Bs[2 * 4096];
  const int NWG = 594;
  int lid = xcd_chunk(blockIdx.x, NWG);
  int rowbase = (lid / 6) * 128;
  int colbase = (lid % 6) * 128;
  gemm_core(As, Bs, Afin, WpT, bp, (void*)outp,
            rowbase, colbase, BATCH * NTOK, DMODEL, 0);
}

// -------------------------------------------------------- rel-pos bias tables
__global__ __launch_bounds__(256) void relbias_kernel(
    const short* __restrict__ qh, const float* __restrict__ rph,
    const float* __restrict__ rpw, short* __restrict__ RelHt, short* __restrict__ RelWt)
{
  int line = blockIdx.x;   // i (mode0) or j (mode1)
  int bh = blockIdx.y;
  int mode = blockIdx.z;
  __shared__ __align__(16) float qt_s[28 * 68];
  __shared__ __align__(16) float rt_s[28 * 68];
  int tid = threadIdx.x;
  const float* rp = (mode == 0) ? rph : rpw;
  for (int idx = tid; idx < 28 * 64; idx += 256) {
    int rr = idx >> 6, c = idx & 63;
    int qi = (mode == 0) ? (1 + line * PHDIM + rr) : (1 + rr * PHDIM + line);
    qt_s[rr * 68 + c] = bf2f(qh[((size_t)bh * NTOK + qi) * HEAD_DIM + c]);
    rt_s[rr * 68 + c] = rp[(line - rr + 27) * HEAD_DIM + c];
  }
  __syncthreads();
  short* dst = (mode == 0) ? RelHt : RelWt;
  for (int o = tid; o < 784; o += 256) {
    int kk = o / PHDIM, rr = o - kk * PHDIM;
    const f32x4* qa = (const f32x4*)&qt_s[rr * 68];
    const f32x4* ra = (const f32x4*)&rt_s[kk * 68];
    f32x4 a4 = (f32x4){0.f, 0.f, 0.f, 0.f};
#pragma unroll
    for (int i = 0; i < 16; ++i) a4 += qa[i] * ra[i];
    float s = (a4[0] + a4[1] + a4[2] + a4[3]) * LOG2E;
    int qrow = (mode == 0) ? (line * PHDIM + rr) : (rr * PHDIM + line);
    dst[((size_t)bh * PHDIM + kk) * 784 + qrow] = f2bf(s);
  }
}

// ------------------------------------------------------------ flash attention
__global__ __launch_bounds__(256) void flash5_kernel(
    const short* __restrict__ qh, const short* __restrict__ kh, const short* __restrict__ vtg,
    const short* __restrict__ RelHt, const short* __restrict__ RelWt,
    short* __restrict__ Afin)
{
  int id = blockIdx.x;
  int slot = id >> 3;
  int bh = (id & 7) * 24 + slot / 13;   // all 13 q-tiles of a bh on one XCD
  int qt = slot - (slot / 13) * 13;
  int qbase = qt * 64;
  int tid = threadIdx.x, wid = tid >> 6, lane = tid & 63;
  int lg = lane >> 4, lq = lane & 15;

  __shared__ __align__(16) short ks[64 * 64];
  __shared__ __align__(16) short vt[64 * 64];
  __shared__ __align__(16) float relh_t[28][64];
  __shared__ __align__(16) float relw_t[28][64];
  __shared__ __align__(16) float axl[4][16];

  for (int idx = tid; idx < 28 * 64; idx += 256) {
    int kk = idx >> 6, ql = idx & 63;
    int qi = qbase + ql;
    float rh = 0.f, rw = 0.f;
    if (qi >= 1 && qi < NTOK) {
      rh = bf2f(RelHt[((size_t)bh * PHDIM + kk) * 784 + qi - 1]);
      rw = bf2f(RelWt[((size_t)bh * PHDIM + kk) * 784 + qi - 1]);
    }
    relh_t[kk][ql] = rh; relw_t[kk][ql] = rw;
  }

  int qi0 = qbase + wid * 16 + lq;
  int qiq = min(qi0, NTOK - 1);
  const short* qrow = qh + ((size_t)bh * NTOK + qiq) * HEAD_DIM;
  bf16x8 bq0 = *(const bf16x8*)(qrow + lg * 8);
  bf16x8 bq1 = *(const bf16x8*)(qrow + 32 + lg * 8);

  float m_l = -3e30f, l_l = 0.f;
  f32x4 acc[4];
#pragma unroll
  for (int ch = 0; ch < 4; ++ch) acc[ch] = (f32x4){0.f, 0.f, 0.f, 0.f};

  const float scale2 = 0.125f * LOG2E;
  int q_local = wid * 16 + lq;
  const short* kbase = kh + (size_t)bh * NTOK * HEAD_DIM;
  const short* vbase = vtg + (size_t)bh * (size_t)HEAD_DIM * NTOK;

  int c0 = tid, c1 = 256 + tid;
  int rr0 = c0 >> 3, j0 = c0 & 7;
  int rr1 = c1 >> 3, j1 = c1 & 7;
  int koff0 = ((rr0 & 15) >> 2) * 16 + (rr0 >> 4) * 4 + (rr0 & 3);
  int koff1 = ((rr1 & 15) >> 2) * 16 + (rr1 >> 4) * 4 + (rr1 & 3);
  int ksw0 = (j0 ^ (rr0 & 7)) << 3;
  int ksw1 = (j1 ^ (rr1 & 7)) << 3;
  int vsw0 = (j0 ^ (rr0 & 7)) << 3;
  int vsw1 = (j1 ^ (rr1 & 7)) << 3;
  const short* vsrc0 = vbase + (size_t)rr0 * NTOK + vsw0;
  const short* vsrc1 = vbase + (size_t)rr1 * NTOK + vsw1;

  auto step_body = [&](int kvb, bool first, bool last) __attribute__((always_inline)) {
    __syncthreads();
    gl_lds16(kbase + (size_t)min(kvb + koff0, NTOK - 1) * HEAD_DIM + ksw0, ks + wid * 512);
    gl_lds16(kbase + (size_t)min(kvb + koff1, NTOK - 1) * HEAD_DIM + ksw1, ks + 2048 + wid * 512);
    gl_lds16(vsrc0 + kvb, vt + wid * 512);
    gl_lds16(vsrc1 + kvb, vt + 2048 + wid * 512);
    __syncthreads();

    int base = kvb + 16 * lg;
    int km1 = base - 1;
    int t = max(km1, 0);
    int ki = t / PHDIM;
    int kj = t - ki * PHDIM;
    if (km1 < 0) kj = -1;

    float p[16];
#pragma unroll
    for (int kt = 0; kt < 4; ++kt) {
      int kl = kt * 16 + lq;
      const char* kp = (const char*)ks + kl * 128;
      int swz = kl & 7;
      bf16x8 aK0 = *(const bf16x8*)(kp + ((lg ^ swz) << 4));
      bf16x8 aK1 = *(const bf16x8*)(kp + (((lg + 4) ^ swz) << 4));
      f32x4 s = (f32x4){0.f, 0.f, 0.f, 0.f};
      __builtin_amdgcn_s_setprio(1);
      s = __builtin_amdgcn_mfma_f32_16x16x32_bf16(aK0, bq0, s, 0, 0, 0);
      s = __builtin_amdgcn_mfma_f32_16x16x32_bf16(aK1, bq1, s, 0, 0, 0);
      __builtin_amdgcn_s_setprio(0);
#pragma unroll
      for (int r = 0; r < 4; ++r) {
        int i = kt * 4 + r;
        float v = s[r] * scale2;
        if (first) {
          int key = base + i;
          if (key >= 1) v += relh_t[ki][q_local] + relw_t[kj][q_local];
        } else if (last) {
          int key = base + i;
          v += relh_t[ki][q_local] + relw_t[kj][q_local];
          if (key >= NTOK) v = -3e30f;
        } else {
          v += relh_t[ki][q_local] + relw_t[kj][q_local];
        }
        p[i] = v;
        ++kj;
        if (kj == PHDIM) { kj = 0; ++ki; }
      }
    }

    float pm = p[0];
#pragma unroll
    for (int i = 1; i < 16; ++i) pm = fmaxf(pm, p[i]);
    pm = fmaxf(pm, __shfl_xor(pm, 16));
    pm = fmaxf(pm, __shfl_xor(pm, 32));
    if (!__all(pm - m_l <= 11.5f)) {
      float mnew = fmaxf(m_l, pm);
      float alpha = fexp2(m_l - mnew);
      m_l = mnew;
      l_l *= alpha;
      if (lg == 0) axl[wid][lq] = alpha;
      f32x4 av = *(const f32x4*)&axl[wid][lg * 4];
#pragma unroll
      for (int ch = 0; ch < 4; ++ch)
#pragma unroll
        for (int r = 0; r < 4; ++r) acc[ch][r] *= av[r];
    }
    float ps = 0.f;
#pragma unroll
    for (int i = 0; i < 16; ++i) { p[i] = fexp2(p[i] - m_l); ps += p[i]; }
    ps += __shfl_xor(ps, 16);
    ps += __shfl_xor(ps, 32);
    l_l += ps;

    bf16x8 pa0, pa1;
#pragma unroll
    for (int j = 0; j < 4; ++j) {
      unsigned u0, u1, v0, v1;
      __builtin_memcpy(&u0, &p[2 * j], 4);
      __builtin_memcpy(&u1, &p[2 * j + 1], 4);
      __builtin_memcpy(&v0, &p[8 + 2 * j], 4);
      __builtin_memcpy(&v1, &p[8 + 2 * j + 1], 4);
      ((unsigned*)&pa0)[j] = (u0 >> 16) | (u1 & 0xFFFF0000u);
      ((unsigned*)&pa1)[j] = (v0 >> 16) | (v1 & 0xFFFF0000u);
    }
    __builtin_amdgcn_s_setprio(1);
#pragma unroll
    for (int ch = 0; ch < 4; ++ch) {
      int d = ch * 16 + lq;
      const char* vrow = (const char*)vt + d * 128;
      int swz = lq & 7;
      bf16x8 bv0 = *(const bf16x8*)(vrow + (((2 * lg + 0) ^ swz) << 4));
      bf16x8 bv1 = *(const bf16x8*)(vrow + (((2 * lg + 1) ^ swz) << 4));
      acc[ch] = __builtin_amdgcn_mfma_f32_16x16x32_bf16(pa0, bv0, acc[ch], 0, 0, 0);
      acc[ch] = __builtin_amdgcn_mfma_f32_16x16x32_bf16(pa1, bv1, acc[ch], 0, 0, 0);
    }
    __builtin_amdgcn_s_setprio(0);
  };

  step_body(0, true, false);
  for (int step = 1; step < 12; ++step) step_body(step * 64, false, false);
  step_body(12 * 64, false, true);

  if (lg == 0) axl[wid][lq] = l_l;
  f32x4 lv = *(const f32x4*)&axl[wid][lg * 4];
  int b = bh / NUM_HEADS, h = bh - b * NUM_HEADS;
#pragma unroll
  for (int r = 0; r < 4; ++r) {
    int qi = qbase + wid * 16 + lg * 4 + r;
    if (qi < NTOK) {
      float inv = 1.f / lv[r];
#pragma unroll
      for (int ch = 0; ch < 4; ++ch) {
        int d = ch * 16 + lq;
        float o = acc[ch][r] * inv + bf2f(qh[((size_t)bh * NTOK + qi) * HEAD_DIM + d]);
        Afin[((size_t)b * NTOK + qi) * DMODEL + h * HEAD_DIM + d] = f2bf(o);
      }
    }
  }
}

// ------------------------------------------------------------------- launcher
extern "C" void kernel_launch(void* const* d_in, const int* in_sizes, int n_in,
                              void* d_out, int out_size, void* d_ws, size_t ws_size,
                              hipStream_t stream)
{
  (void)in_sizes; (void)n_in; (void)out_size; (void)ws_size;
  const float* x   = (const float*)d_in[0];
  const float* pqw = (const float*)d_in[1];
  const float* pkw = (const float*)d_in[2];
  const float* pvw = (const float*)d_in[3];
  const float* gq  = (const float*)d_in[4];
  const float* bq_ = (const float*)d_in[5];
  const float* gk  = (const float*)d_in[6];
  const float* bk_ = (const float*)d_in[7];
  const float* gv  = (const float*)d_in[8];
  const float* bv_ = (const float*)d_in[9];
  const float* wq  = (const float*)d_in[10];
  const float* bqp = (const float*)d_in[11];
  const float* wk  = (const float*)d_in[12];
  const float* bkp = (const float*)d_in[13];
  const float* wv  = (const float*)d_in[14];
  const float* bvp = (const float*)d_in[15];
  const float* wp  = (const float*)d_in[16];
  const float* bpp = (const float*)d_in[17];
  const float* rph = (const float*)d_in[18];
  const float* rpw = (const float*)d_in[19];

  char* ws = (char*)d_ws;
  size_t off = 0;
  auto alloc = [&](size_t bytes) -> void* {
    void* p = ws + off; off += (bytes + 255) & ~(size_t)255; return p;
  };
  const size_t MROWS = (size_t)BATCH * NTOK;   // 12560
  short* Pq  = (short*)alloc(MROWS * DMODEL * 2);
  short* Pk  = (short*)alloc(MROWS * DMODEL * 2);
  short* Pv  = (short*)alloc(MROWS * DMODEL * 2);
  short* WqT = (short*)alloc((size_t)DMODEL * DMODEL * 2);
  short* WkT = (short*)alloc((size_t)DMODEL * DMODEL * 2);
  short* WvT = (short*)alloc((size_t)DMODEL * DMODEL * 2);
  short* WpT = (short*)alloc((size_t)DMODEL * DMODEL * 2);
  short* qhd = (short*)alloc(MROWS * DMODEL * 2 + 4096);
  short* khd = (short*)alloc(MROWS * DMODEL * 2 + 4096);
  short* vtg = (short*)alloc(MROWS * DMODEL * 2 + 8192);  // transposed V
  short* RelHt = (short*)alloc((size_t)BHCNT * 784 * 28 * 2);
  short* RelWt = (short*)alloc((size_t)BHCNT * 784 * 28 * 2);
  short* Afin = (short*)alloc(MROWS * DMODEL * 2);

  pool_ln_kernel<<<dim3(16 * 197), 192, 0, stream>>>(
      x, pqw, pkw, pvw, gq, bq_, gk, bk_, gv, bv_, Pq, Pk, Pv);
  trans_kernel<<<dim3(24, 24, 4), dim3(32, 8), 0, stream>>>(
      wq, wk, wv, wp, WqT, WkT, WvT, WpT);
  gemm_qkv_kernel<<<dim3(1782), 256, 0, stream>>>(
      Pq, WqT, bqp, qhd, Pk, WkT, bkp, khd, WvT, Pv, bvp, vtg);
  relbias_kernel<<<dim3(28, BHCNT, 2), 256, 0, stream>>>(qhd, rph, rpw, RelHt, RelWt);
  flash5_kernel<<<dim3(2496), 256, 0, stream>>>(qhd, khd, vtg, RelHt, RelWt, Afin);
  gemm_proj_kernel<<<dim3(594), 256, 0, stream>>>(Afin, WpT, bpp, (float*)d_out);
}